// Round 3
// baseline (496.000 us; speedup 1.0000x reference)
//
#include <hip/hip_runtime.h>
#include <stdint.h>

// Problem constants (fixed by setup_inputs)
#define PN     512
#define NFREE  50000
#define NCND   100000
#define NNODE  100512
#define NEDGE  300000
#define KK     10
#define NLOOP  5
#define EPSV   1e-5f

#define GRID   128
#define NCELL  (GRID*GRID)

// fixed spatial-hash bounds: candidates ~N(0,1); clamping keeps exactness
#define XMINF  (-6.f)
#define YMINF  (-6.f)
#define SPANF  12.f
#define IVCW   ((float)GRID / SPANF)

#define HSIZE  8192
#define HMASK  (HSIZE-1)
#define E0CAP  4096
#define EMPTYK 0xFFFFFFFFFFFFFFFFull

#define NCB    ((NCND+255)/256)    // 391
#define NEB    ((NEDGE+255)/256)   // 1172

// workspace layout (bytes) — ~2.7 MB
#define OFF_HASH    ((size_t)0)
#define OFF_CPOS    (OFF_HASH    + (size_t)HSIZE*8)
#define OFF_SCND    (OFF_CPOS    + 800000)               // float4/cand, cell-sorted
#define OFF_CSTART  (OFF_SCND    + 1600000)              // NCELL+1 ints
#define OFF_COFS    (OFF_CSTART  + 65600)
#define OFF_MOM     (OFF_COFS    + 65600)                // 10 floats (cand moments)
#define OFF_WCU     (OFF_MOM     + 64)
#define OFF_WCV     (OFF_WCU     + 4096)
#define OFF_BU      (OFF_WCV     + 4096)
#define OFF_BV      (OFF_BU      + 128)
#define OFF_CPATH   (OFF_BV      + 128)
#define OFF_CFREE   (OFF_CPATH   + 128)
#define OFF_CCOL    (OFF_CFREE   + 128)
#define OFF_PATH    (OFF_CCOL    + 128)                  // 16-aligned
#define OFF_E0S     (OFF_PATH    + 4096)
#define OFF_E0D     (OFF_E0S     + (size_t)E0CAP*4)
#define OFF_DEG0    (OFF_E0D     + (size_t)E0CAP*4)
#define OFF_E0C     (OFF_DEG0    + 2048)
#define OFF_E0START (OFF_E0C     + 64)                   // 513 ints (pad 2112)
#define OFF_E0OFS   (OFF_E0START + 2112)
#define OFF_E0CSRS  (OFF_E0OFS   + 2048)                 // E0CAP ints

// E0S/E0D are dead after k_scan2 — reuse for the fused persistent loop:
#define OFF_PATH2   OFF_E0S     // ping-pong path buffer
#define OFF_GBAR    OFF_E0D     // per-generation arrival counters [NLOOP]

#define WS_F(o)  ((float*)(ws + (o)))
#define WS_I(o)  ((int*)(ws + (o)))
#define WS_H(o)  ((unsigned long long*)(ws + (o)))

__device__ __forceinline__ bool lexless(float da, int ia, float db, int ib) {
  return (da < db) || (da == db && ia < ib);
}

__device__ __forceinline__ uint32_t hslot(unsigned long long key) {
  return (uint32_t)((key * 0x9E3779B97F4A7C15ull) >> 40) & HMASK;
}

// ---- cross-XCD path IO: RELAXED agent-scope atomics (sc1 bypass, NO cache
// invalidate / writeback). This is the fix for round-1's 94MB flush storm.
__device__ __forceinline__ float agl(const float* p) {
  unsigned v = __hip_atomic_load((const unsigned*)p, __ATOMIC_RELAXED,
                                 __HIP_MEMORY_SCOPE_AGENT);
  return __uint_as_float(v);
}
__device__ __forceinline__ void ags(float* p, float v) {
  __hip_atomic_store((unsigned*)p, __float_as_uint(v), __ATOMIC_RELAXED,
                     __HIP_MEMORY_SCOPE_AGENT);
}

// per-generation grid barrier: arrival = RELEASE fetch_add (orders my path
// stores; L2 is clean in-loop so the writeback is ~free), wait = RELAXED
// polling (no invalidate!). No reset, no ABA: one counter per generation.
__device__ __forceinline__ void gridbar(int* arr, int gen) {
  __syncthreads();
  if (threadIdx.x == 0) {
    int c = __hip_atomic_fetch_add(&arr[gen], 1, __ATOMIC_RELEASE,
                                   __HIP_MEMORY_SCOPE_AGENT) + 1;
    if (c < (int)gridDim.x) {
      while (__hip_atomic_load(&arr[gen], __ATOMIC_RELAXED,
                               __HIP_MEMORY_SCOPE_AGENT) < (int)gridDim.x)
        __builtin_amdgcn_s_sleep(32);
    }
  }
  __syncthreads();
}

// BN mean/rstd from analytic moments (cand moments in MOM + path moments pm*)
__device__ __forceinline__ void bn_from_moments(const char* ws,
    float w0, float w1, float cp, float clsF, float clsC,
    float pm0, float pm1, float pm00, float pm11, float pm01,
    float* meano, float* rstdo) {
  const float* M = (const float*)(ws + OFF_MOM);
  float sF0=M[0], sF1=M[1], sF00=M[2], sF11=M[3], sF01=M[4];
  float sC0=M[5], sC1=M[6], sC00=M[7], sC11=M[8], sC01=M[9];
  const float NC = (float)(NCND - NFREE);
  float sh  = w0*(sF0+sC0+pm0) + w1*(sF1+sC1+pm1)
            + (float)NFREE*clsF + NC*clsC + (float)PN*cp;
  float sh2 = w0*w0*(sF00+sC00+pm00) + w1*w1*(sF11+sC11+pm11)
            + 2.f*w0*w1*(sF01+sC01+pm01)
            + 2.f*w0*(clsF*sF0 + clsC*sC0 + cp*pm0)
            + 2.f*w1*(clsF*sF1 + clsC*sC1 + cp*pm1)
            + (float)NFREE*clsF*clsF + NC*clsC*clsC + (float)PN*cp*cp;
  float mean = sh  * (1.f / NNODE);
  float ex2  = sh2 * (1.f / NNODE);
  float var  = ex2 - mean * mean;
  *meano = mean;
  *rstdo = 1.0f / sqrtf(var + EPSV);
}

#define INSERT10(d2v, jv)                                                  \
  if (lexless((d2v), (jv), bd[9], bi[9])) {                                \
    bool placed = false;                                                   \
    _Pragma("unroll")                                                      \
    for (int k = 9; k > 0; k--) {                                          \
      bool shift = !placed && lexless((d2v), (jv), bd[k-1], bi[k-1]);      \
      bool here  = !placed && !shift;                                      \
      if (here)       { bd[k] = (d2v); bi[k] = (jv); placed = true; }      \
      else if (shift) { bd[k] = bd[k-1]; bi[k] = bi[k-1]; }                \
    }                                                                      \
    if (!placed) { bd[0] = (d2v); bi[0] = (jv); }                          \
  }

// wave top-10 pop-merge -> LDS slots [base..base+9] (lane r writes rank r)
#define WSTORE10(base) do {                                                \
    float cd[10]; int ci[10];                                              \
    _Pragma("unroll")                                                      \
    for (int k = 0; k < 10; k++) { cd[k] = bd[k]; ci[k] = bi[k]; }         \
    _Pragma("unroll")                                                      \
    for (int r = 0; r < 10; r++) {                                         \
      float md = cd[0]; int mi = ci[0];                                    \
      _Pragma("unroll")                                                    \
      for (int off = 32; off >= 1; off >>= 1) {                            \
        float od = __shfl_xor(md, off);                                    \
        int   oi = __shfl_xor(mi, off);                                    \
        if (lexless(od, oi, md, mi)) { md = od; mi = oi; }                 \
      }                                                                    \
      bool win = (cd[0] == md) && (ci[0] == mi);                           \
      if (win) {                                                           \
        _Pragma("unroll")                                                  \
        for (int k = 0; k < 9; k++) { cd[k] = cd[k+1]; ci[k] = ci[k+1]; }  \
        cd[9] = 3.4e38f; ci[9] = 0x7FFFFFFF;                               \
      }                                                                    \
      if (lane == r) { sD[(base)+r] = md; sI[(base)+r] = mi; }             \
    }                                                                      \
  } while (0)

// exact rank-merge of the 40 LDS entries -> sMD/sMI[0..9] (wave 0 only)
#define MERGE40() do {                                                     \
    float de = (lane < 40) ? sD[lane] : 3.4e38f;                           \
    int   ie = (lane < 40) ? sI[lane] : 0x7FFFFFFF;                        \
    int rank = 0;                                                          \
    for (int f = 0; f < 40; f++) {                                         \
      float df = sD[f]; int iff = sI[f];                                   \
      bool less = lexless(df, iff, de, ie) ||                              \
                  (df == de && iff == ie && f < lane);                     \
      rank += less ? 1 : 0;                                                \
    }                                                                      \
    if (lane < 40 && rank < 10) { sMD[rank] = de; sMI[rank] = ie; }        \
  } while (0)

// scan rows of box [xA..xB]x[yA..yB] with y % 4 == wv (4-wave split);
// each row is a contiguous scnd span, lanes stride it (coalesced).
#define SCAN_BOX4(xA, xB, yA, yB) do {                                     \
    for (int _y = (yA) + wv; _y <= (yB); _y += 4) {                        \
      int _s = cst[_y*GRID + (xA)], _e = cst[_y*GRID + (xB) + 1];          \
      for (int _t = _s + lane; _t < _e; _t += 64) {                        \
        float4 _q = scnd[_t];                                              \
        float _d2 = (psq + _q.z) - 2.f * fmaf(p1, _q.y, p0 * _q.x);        \
        int _j = __float_as_int(_q.w);                                     \
        INSERT10(_d2, _j);                                                 \
      }                                                                    \
    }                                                                      \
  } while (0)

// ---------------- setup kernels ----------------

__global__ __launch_bounds__(256) void k_init0(char* __restrict__ ws,
                                               const float* __restrict__ path_in) {
  unsigned i = blockIdx.x * 256u + threadIdx.x;       // grid = 65 → 16640 ids
  if (i < HSIZE)   WS_H(OFF_HASH)[i] = EMPTYK;
  if (i < NCELL+1) WS_I(OFF_CSTART)[i] = 0;
  if (i < 1024)    WS_F(OFF_PATH)[i] = path_in[i];
  if (i < 512)     WS_I(OFF_DEG0)[i] = 0;
  if (i < 16)      WS_F(OFF_MOM)[i] = 0.f;
  if (i == 0)      *WS_I(OFF_E0C) = 0;
}

// roles: b<NCB cand(pos/moments/hist) | b<NCB+NEB edge filter+dedup | last wprep
__global__ __launch_bounds__(256) void k_setupA(char* __restrict__ ws,
    const float* __restrict__ freep, const float* __restrict__ collp,
    const int* __restrict__ ei,
    const float* __restrict__ ncw1, const float* __restrict__ ncb1,
    const float* __restrict__ m0w1, const float* __restrict__ m0b1,
    const float* __restrict__ ncw2, const float* __restrict__ ncb2) {
  int b = blockIdx.x, tid = threadIdx.x;
  if (b < NCB) {
    __shared__ float s10[4][10];
    int j = b*256 + tid;
    bool valid = (j < NCND);
    float c0 = 0.f, c1 = 0.f;
    if (valid) {
      if (j < NFREE) { c0 = freep[2*j];          c1 = freep[2*j+1]; }
      else           { c0 = collp[2*(j-NFREE)];  c1 = collp[2*(j-NFREE)+1]; }
      ((float2*)(ws + OFF_CPOS))[j] = make_float2(c0, c1);
    }
    bool isF = valid && (j < NFREE), isC = valid && (j >= NFREE);
    float v[10];
    v[0]=isF?c0:0.f; v[1]=isF?c1:0.f; v[2]=isF?c0*c0:0.f; v[3]=isF?c1*c1:0.f; v[4]=isF?c0*c1:0.f;
    v[5]=isC?c0:0.f; v[6]=isC?c1:0.f; v[7]=isC?c0*c0:0.f; v[8]=isC?c1*c1:0.f; v[9]=isC?c0*c1:0.f;
    #pragma unroll
    for (int q = 0; q < 10; q++)
      #pragma unroll
      for (int off = 32; off >= 1; off >>= 1) v[q] += __shfl_xor(v[q], off);
    int wv = tid >> 6, lane = tid & 63;
    if (lane == 0) {
      #pragma unroll
      for (int q = 0; q < 10; q++) s10[wv][q] = v[q];
    }
    if (valid) {
      int cx = min(GRID-1, max(0, (int)((c0 - XMINF) * IVCW)));
      int cy = min(GRID-1, max(0, (int)((c1 - YMINF) * IVCW)));
      atomicAdd(&WS_I(OFF_CSTART)[cy*GRID + cx], 1);
    }
    __syncthreads();
    if (tid < 10)
      atomicAdd(&WS_F(OFF_MOM)[tid], s10[0][tid]+s10[1][tid]+s10[2][tid]+s10[3][tid]);
  } else if (b < NCB + NEB) {
    int e = (b - NCB)*256 + tid;
    if (e >= NEDGE) return;
    int src = ei[e], dst = ei[NEDGE + e];
    if (dst >= PN) return;                         // only dst<PN edges matter
    unsigned long long key = (unsigned long long)src * NNODE + (unsigned long long)dst;
    unsigned long long* hash = WS_H(OFF_HASH);
    uint32_t slot = hslot(key);
    for (;;) {
      unsigned long long prev = atomicCAS(&hash[slot], EMPTYK, key);
      if (prev == EMPTYK) {
        int pos = atomicAdd(WS_I(OFF_E0C), 1);
        if (pos < E0CAP) {
          WS_I(OFF_E0S)[pos] = src;
          WS_I(OFF_E0D)[pos] = dst;
          atomicAdd(&WS_I(OFF_DEG0)[dst], 1);
        }
        break;
      }
      if (prev == key) break;
      slot = (slot + 1) & HMASK;
    }
  } else {
    __shared__ float Wu[1024], Wv[1024];
    for (int it = 0; it < 4; it++) {
      int idx = it*256 + tid, k = idx >> 5, g = idx & 31;
      float a = m0w1[k*32+g], b2 = m0w1[(k+32)*32+g], c = m0w1[(k+64)*32+g];
      Wu[idx] = a + b2;  Wv[idx] = c - a;
    }
    __syncthreads();
    for (int it = 0; it < 4; it++) {
      int idx = it*256 + tid, k = idx >> 5, g = idx & 31;
      float au = 0.f, av = 0.f;
      #pragma unroll
      for (int f = 0; f < 32; f++) {
        float w2 = ncw2[k*32+f];
        au = fmaf(w2, Wu[f*32+g], au);
        av = fmaf(w2, Wv[f*32+g], av);
      }
      WS_F(OFF_WCU)[idx] = au;  WS_F(OFF_WCV)[idx] = av;
    }
    if (tid < 32) {
      float bu = 0.f, bv = 0.f;
      #pragma unroll
      for (int f = 0; f < 32; f++) {
        bu = fmaf(ncb2[f], Wu[f*32+tid], bu);
        bv = fmaf(ncb2[f], Wv[f*32+tid], bv);
      }
      WS_F(OFF_BU)[tid] = bu;
      WS_F(OFF_BV)[tid] = bv + m0b1[tid];        // fold mp0_b1 into dst-side
      WS_F(OFF_CPATH)[tid] = ncw1[64+tid]  + ncb1[tid];
      WS_F(OFF_CFREE)[tid] = ncw1[96+tid]  + ncb1[tid];
      WS_F(OFF_CCOL)[tid]  = ncw1[128+tid] + ncb1[tid];
    }
  }
}

// b==0: exclusive scan of cell counts | b==1: CSR build of fixed edges
__global__ __launch_bounds__(256) void k_scan2(char* __restrict__ ws) {
  int b = blockIdx.x, tid = threadIdx.x;
  if (b == 0) {
    __shared__ int part[256];
    int* cnt = WS_I(OFF_CSTART);
    int base = tid * (NCELL/256);
    int sum = 0;
    for (int k = 0; k < NCELL/256; k++) sum += cnt[base+k];
    part[tid] = sum;
    __syncthreads();
    for (int off = 1; off < 256; off <<= 1) {
      int t = (tid >= off) ? part[tid - off] : 0;
      __syncthreads();
      part[tid] += t;
      __syncthreads();
    }
    int run = part[tid] - sum;
    for (int k = 0; k < NCELL/256; k++) {
      int c = cnt[base+k];
      cnt[base+k] = run;
      WS_I(OFF_COFS)[base+k] = run;
      run += c;
    }
    if (tid == 255) cnt[NCELL] = run;
  } else {
    __shared__ int sc[512];
    sc[tid]     = WS_I(OFF_DEG0)[tid];
    sc[256+tid] = WS_I(OFF_DEG0)[256+tid];
    __syncthreads();
    if (tid == 0) {
      int run = 0;
      for (int i = 0; i < 512; i++) { int c = sc[i]; sc[i] = run; run += c; }
      WS_I(OFF_E0START)[512] = run;
    }
    __syncthreads();
    WS_I(OFF_E0START)[tid]     = sc[tid];
    WS_I(OFF_E0START)[256+tid] = sc[256+tid];
    WS_I(OFF_E0OFS)[tid]       = sc[tid];
    WS_I(OFF_E0OFS)[256+tid]   = sc[256+tid];
    __syncthreads();
    int n = *WS_I(OFF_E0C); if (n > E0CAP) n = E0CAP;
    for (int e = tid; e < n; e += 256) {
      int dst = WS_I(OFF_E0D)[e];
      int pos = atomicAdd(&WS_I(OFF_E0OFS)[dst], 1);
      WS_I(OFF_E0CSRS)[pos] = WS_I(OFF_E0S)[e];
    }
  }
}

__global__ __launch_bounds__(256) void k_scatter(char* __restrict__ ws) {
  // E0D is dead after k_scan2; zero the generation counters that alias it.
  if (blockIdx.x == 0 && threadIdx.x < NLOOP) WS_I(OFF_GBAR)[threadIdx.x] = 0;
  int j = blockIdx.x * 256 + threadIdx.x;
  if (j >= NCND) return;
  float2 c = ((const float2*)(ws + OFF_CPOS))[j];
  int cx = min(GRID-1, max(0, (int)((c.x - XMINF) * IVCW)));
  int cy = min(GRID-1, max(0, (int)((c.y - YMINF) * IVCW)));
  int pos = atomicAdd(&WS_I(OFF_COFS)[cy*GRID + cx], 1);
  ((float4*)(ws + OFF_SCND))[pos] =
      make_float4(c.x, c.y, c.x*c.x + c.y*c.y, __int_as_float(j));
}

// ---------------- the fused persistent per-loop kernel, take 2 ----------------
// block = one path node, 256 threads (4 waves), all 5 iterations in one launch.
// Cross-iteration state is ONLY the 4KB path: accessed via RELAXED agent-scope
// atomics (cache-bypass, no invalidate). Barrier = per-generation counters,
// RELEASE arrival + RELAXED spin. Read-only data (scnd/cstart/cpos/weights)
// stays L2-hot across iterations — unlike the 5-dispatch version, which paid
// a full L2 invalidate + 2.9MB refetch per dispatch.
__global__ __launch_bounds__(256, 2) void k_loop_fused2(char* __restrict__ ws,
    const float* __restrict__ ncw1, const float* __restrict__ gamma,
    const float* __restrict__ beta, const float* __restrict__ ncw2,
    const float* __restrict__ ncb2, const float* __restrict__ m0w2,
    const float* __restrict__ m0b2, const float* __restrict__ m1w1,
    const float* __restrict__ m1b1, const float* __restrict__ m1w2,
    const float* __restrict__ m1b2, const float* __restrict__ snw,
    const float* __restrict__ snb, float* __restrict__ outp) {
  __shared__ float sD[40];
  __shared__ int   sI[40];
  __shared__ float sMD[10];
  __shared__ int   sMI[10];
  __shared__ int   sbox[9];           // xL,xR,yL,yR, xL2,xR2,yL2,yR2, skip
  __shared__ int   sRC[4];            // per-wave phase-A counts
  __shared__ float sS[4][32];         // per-wave partial S
  __shared__ float sPM[4][5];         // per-wave partial path moments
  int tid = threadIdx.x, lane = tid & 63, wv = tid >> 6;
  int node = blockIdx.x;
  const float4* scnd = (const float4*)(ws + OFF_SCND);
  const int* cst = WS_I(OFF_CSTART);
  int* bar = WS_I(OFF_GBAR);

  // loop-invariant per-lane state (read-only, cached)
  int fA = lane & 31;
  const float w0 = ncw1[fA], w1 = ncw1[32+fA];
  const float cp   = WS_F(OFF_CPATH)[fA];
  const float clsF = WS_F(OFF_CFREE)[fA];
  const float clsC = WS_F(OFF_CCOL)[fA];
  const float gm = gamma[fA], bt = beta[fA];
  const float buf = WS_F(OFF_BU)[fA];
  const float bvf = WS_F(OFF_BV)[fA];
  const float* wcu = WS_F(OFF_WCU);
  const float* wcv = WS_F(OFF_WCV);
  const int s0 = WS_I(OFF_E0START)[node], s1 = WS_I(OFF_E0START)[node+1];
  const int nfix = s1 - s0;
  const int fsrc = (lane < nfix) ? WS_I(OFF_E0CSRS)[s0 + lane] : -1;

  for (int l = 0; l < NLOOP; ++l) {
    float* pcur = WS_F((l & 1) ? OFF_PATH2 : OFF_PATH);
    float* pnxt = WS_F((l & 1) ? OFF_PATH  : OFF_PATH2);
    float p0 = agl(&pcur[2*node]), p1 = agl(&pcur[2*node+1]);
    float psq = p0*p0 + p1*p1;

    // ---- phase A: probe R = 1<<wv in parallel; each wave also computes its
    //      quarter of the BN path moments (bypass loads, 2 elems/lane) ----
    int cx = min(GRID-1, max(0, (int)((p0 - XMINF) * IVCW)));
    int cy = min(GRID-1, max(0, (int)((p1 - YMINF) * IVCW)));
    {
      int Rw = 1 << wv;
      int xA = max(cx-Rw, 0), xB = min(cx+Rw, GRID-1);
      int yA = max(cy-Rw, 0), yB = min(cy+Rw, GRID-1);
      int cnt = 0;
      for (int y = yA + lane; y <= yB; y += 64)
        cnt += cst[y*GRID + xB + 1] - cst[y*GRID + xA];
      #pragma unroll
      for (int off = 32; off >= 1; off >>= 1) cnt += __shfl_xor(cnt, off);
      if (lane == 0) sRC[wv] = cnt;
    }
    {
      float pm0=0,pm1=0,pm00=0,pm11=0,pm01=0;
      #pragma unroll
      for (int rr2 = 0; rr2 < 2; rr2++) {
        int r2 = wv*128 + rr2*64 + lane;
        float qx = agl(&pcur[2*r2]), qy = agl(&pcur[2*r2+1]);
        pm0+=qx; pm1+=qy; pm00+=qx*qx; pm11+=qy*qy; pm01+=qx*qy;
      }
      #pragma unroll
      for (int off = 32; off >= 1; off >>= 1) {
        pm0+=__shfl_xor(pm0,off); pm1+=__shfl_xor(pm1,off);
        pm00+=__shfl_xor(pm00,off); pm11+=__shfl_xor(pm11,off);
        pm01+=__shfl_xor(pm01,off);
      }
      if (lane == 0) {
        sPM[wv][0]=pm0; sPM[wv][1]=pm1; sPM[wv][2]=pm00;
        sPM[wv][3]=pm11; sPM[wv][4]=pm01;
      }
    }
    __syncthreads();
    if (wv == 0) {
      int R = 0;
      if (sRC[3] >= KK) R = 8;
      if (sRC[2] >= KK) R = 4;
      if (sRC[1] >= KK) R = 2;
      if (sRC[0] >= KK) R = 1;
      int xLa, xRa, yLa, yRa;
      if (R == 0) {                       // rare sparse-region fallback
        R = 16;
        for (;;) {
          xLa = max(cx-R, 0); xRa = min(cx+R, GRID-1);
          yLa = max(cy-R, 0); yRa = min(cy+R, GRID-1);
          int cnt = 0;
          for (int y = yLa + lane; y <= yRa; y += 64)
            cnt += cst[y*GRID + xRa + 1] - cst[y*GRID + xLa];
          #pragma unroll
          for (int off = 32; off >= 1; off >>= 1) cnt += __shfl_xor(cnt, off);
          if (cnt >= KK || R >= GRID) break;
          R <<= 1;
        }
      } else {
        xLa = max(cx-R, 0); xRa = min(cx+R, GRID-1);
        yLa = max(cy-R, 0); yRa = min(cy+R, GRID-1);
      }
      if (lane == 0) { sbox[0]=xLa; sbox[1]=xRa; sbox[2]=yLa; sbox[3]=yRa; }
    }
    __syncthreads();
    int xL = sbox[0], xR = sbox[1], yL = sbox[2], yR = sbox[3];

    // ---- phase B: 4-wave split scan of seed box ----
    float bd[10]; int bi[10];
    #pragma unroll
    for (int k = 0; k < 10; k++) { bd[k] = 3.4e38f; bi[k] = 0x7FFFFFFF; }
    SCAN_BOX4(xL, xR, yL, yR);
    WSTORE10(wv*10);
    __syncthreads();
    if (wv == 0) MERGE40();
    __syncthreads();

    // ---- phase C box + containment test (skip if seed scan already exact) --
    if (tid == 0) {
      float r = sqrtf(sMD[9]) * 1.000002f;
      int xL2 = min(GRID-1, max(0, (int)((p0 - r - XMINF) * IVCW)));
      int xR2 = min(GRID-1, max(0, (int)((p0 + r - XMINF) * IVCW)));
      int yL2 = min(GRID-1, max(0, (int)((p1 - r - YMINF) * IVCW)));
      int yR2 = min(GRID-1, max(0, (int)((p1 + r - YMINF) * IVCW)));
      sbox[4]=xL2; sbox[5]=xR2; sbox[6]=yL2; sbox[7]=yR2;
      sbox[8] = (xL2 >= xL && xR2 <= xR && yL2 >= yL && yR2 <= yR) ? 1 : 0;
    }
    __syncthreads();
    if (!sbox[8]) {
      int xL2 = sbox[4], xR2 = sbox[5], yL2 = sbox[6], yR2 = sbox[7];
      #pragma unroll
      for (int k = 0; k < 10; k++) { bd[k] = 3.4e38f; bi[k] = 0x7FFFFFFF; }
      SCAN_BOX4(xL2, xR2, yL2, yR2);
      WSTORE10(wv*10);
      __syncthreads();
      if (wv == 0) MERGE40();
      __syncthreads();
    }

    // ======== all 4 waves work from here ========

    // dedup kNN vs fixed edges — pure register shfl
    int selIdx = (lane < KK) ? sMI[lane] : 0;
    int srcg   = (lane < KK) ? selIdx + PN : -1;
    int keep   = (lane < KK) ? 1 : 0;
    for (int t = 0; t < min(nfix, 64); t++) {
      int fs = __shfl(fsrc, t);
      if (fs == srcg) keep = 0;
    }
    for (int t = 64; t < nfix; t++) {            // ~never
      int fs = WS_I(OFF_E0CSRS)[s0 + t];
      if (fs == srcg) keep = 0;
    }
    unsigned long long kmask = __ballot(keep);
    int deg = (int)__popcll(kmask) + nfix;

    // parallel prefetch of per-edge data: lane e holds edge e
    int t2 = lane - KK;
    int srcb = __shfl(fsrc, (t2 & 63));          // uniform-exec shfl
    float eq0 = 0.f, eq1 = 0.f; int ecl = 1, eva = 0;
    if (lane < KK) {
      eva = keep;
      if (keep) {
        eq0 = WS_F(OFF_CPOS)[2*selIdx];
        eq1 = WS_F(OFF_CPOS)[2*selIdx+1];
        ecl = (selIdx < NFREE) ? 1 : 2;
      }
    } else if (t2 < nfix) {                      // t2 <= 53 always
      eva = 1;
      if (srcb < PN) { eq0 = agl(&pcur[2*srcb]); eq1 = agl(&pcur[2*srcb+1]); ecl = 0; }
      else {
        int jj = srcb - PN;
        eq0 = WS_F(OFF_CPOS)[2*jj]; eq1 = WS_F(OFF_CPOS)[2*jj+1];
        ecl = (jj < NFREE) ? 1 : 2;
      }
    }

    // BN from the per-wave quarter moments (published pre-phase-B barrier)
    float pm0  = sPM[0][0]+sPM[1][0]+sPM[2][0]+sPM[3][0];
    float pm1  = sPM[0][1]+sPM[1][1]+sPM[2][1]+sPM[3][1];
    float pm00 = sPM[0][2]+sPM[1][2]+sPM[2][2]+sPM[3][2];
    float pm11 = sPM[0][3]+sPM[1][3]+sPM[2][3]+sPM[3][3];
    float pm01 = sPM[0][4]+sPM[1][4]+sPM[2][4]+sPM[3][4];
    float mean, rstd;
    bn_from_moments(ws, w0, w1, cp, clsF, clsC, pm0, pm1, pm00, pm11, pm01,
                    &mean, &rstd);

    // xn_dst and v[dst] (per wave)
    float hD = fmaf(p1, w1, fmaf(p0, w0, cp));
    float xnd = fmaf((hD - mean) * rstd, gm, bt);
    xnd = xnd > 0.f ? xnd : 0.f;
    float av = bvf;
    #pragma unroll
    for (int m = 0; m < 32; m++) av = fmaf(__shfl(xnd, m), wcv[m*32+fA], av);

    // S over edges: 8-way parallel (4 waves x 2 half-waves), uniform trips
    int hf = lane >> 5;
    int Etot = KK + min(nfix, 54);
    int nT = (Etot + 7) >> 3;
    float S = 0.f;
    for (int t = 0; t < nT; t++) {
      int e  = (t << 3) + (wv << 1) + hf;
      int ee = e & 63;
      int   ev = __shfl(eva, ee);
      float q0 = __shfl(eq0, ee), q1 = __shfl(eq1, ee);
      int   ec = __shfl(ecl, ee);
      float clsv = (ec == 0) ? cp : ((ec == 1) ? clsF : clsC);
      float hq = fmaf(q1, w1, fmaf(q0, w0, clsv));
      float xnf = fmaf((hq - mean) * rstd, gm, bt);
      xnf = xnf > 0.f ? xnf : 0.f;
      float au = buf;
      #pragma unroll
      for (int m = 0; m < 32; m++)
        au = fmaf(__shfl(xnf, m, 32), wcu[m*32+fA], au);
      float rr = au + av;
      if (e < Etot && ev && rr > 0.f) S += rr;
    }
    S += __shfl_xor(S, 32);                      // combine half-waves
    if (lane < 32) sS[wv][lane] = S;
    __syncthreads();

    if (wv == 0) {
      float St = sS[0][fA] + sS[1][fA] + sS[2][fA] + sS[3][fA];
      for (int t = 54; t < nfix; t++) {          // ~never: overflow tail
        int src = WS_I(OFF_E0CSRS)[s0 + t];
        float q0, q1, clsv;
        if (src < PN) { q0 = agl(&pcur[2*src]); q1 = agl(&pcur[2*src+1]); clsv = cp; }
        else {
          int jj = src - PN;
          q0 = WS_F(OFF_CPOS)[2*jj]; q1 = WS_F(OFF_CPOS)[2*jj+1];
          clsv = (jj < NFREE) ? clsF : clsC;
        }
        float hq = fmaf(q1, w1, fmaf(q0, w0, clsv));
        float xnf = fmaf((hq - mean) * rstd, gm, bt);
        xnf = xnf > 0.f ? xnf : 0.f;
        float au = buf;
        #pragma unroll
        for (int m = 0; m < 32; m++) au = fmaf(__shfl(xnf, m), wcu[m*32+fA], au);
        float rr = au + av;
        if (rr > 0.f) St += rr;
      }

      // epilogue: four 32x32 GEMVs via shfl-dots
      float o = (float)deg * m0b2[fA];
      #pragma unroll
      for (int k = 0; k < 32; k++) o = fmaf(__shfl(St, k), m0w2[k*32+fA], o);
      float t1 = m1b1[fA];
      #pragma unroll
      for (int k = 0; k < 32; k++) t1 = fmaf(__shfl(o, k), m1w1[k*32+fA], t1);
      t1 = t1 > 0.f ? t1 : 0.f;
      float g2 = m1b2[fA];
      #pragma unroll
      for (int k = 0; k < 32; k++) g2 = fmaf(__shfl(t1, k), m1w2[k*32+fA], g2);
      float x = ncb2[fA];
      #pragma unroll
      for (int k = 0; k < 32; k++) x = fmaf(__shfl(xnd, k), ncw2[k*32+fA], x);
      float hh = x + g2;
      float r0 = hh * snw[2*fA], r1 = hh * snw[2*fA+1];
      #pragma unroll
      for (int off = 16; off >= 1; off >>= 1) {
        r0 += __shfl_xor(r0, off);
        r1 += __shfl_xor(r1, off);
      }
      if (lane == 0) {
        float np0, np1;
        if (node == 0 || node == PN-1) { np0 = p0; np1 = p1; }  // endpoints fixed
        else { np0 = snb[0] + r0; np1 = snb[1] + r1; }
        if (l == NLOOP-1) { outp[2*node] = np0; outp[2*node+1] = np1; }
        else { ags(&pnxt[2*node], np0); ags(&pnxt[2*node+1], np1); }
      }
    }

    if (l < NLOOP-1) gridbar(bar, l);
  }
}

// ---------------- host launch ----------------

extern "C" void kernel_launch(void* const* d_in, const int* in_sizes, int n_in,
                              void* d_out, int out_size, void* d_ws, size_t ws_size,
                              hipStream_t stream) {
  const float* path  = (const float*)d_in[0];
  const float* freep = (const float*)d_in[1];
  const float* collp = (const float*)d_in[2];
  const int*   ei    = (const int*)d_in[4];
  const float* ncw1  = (const float*)d_in[6];
  const float* ncb1  = (const float*)d_in[7];
  const float* gamma = (const float*)d_in[8];
  const float* beta  = (const float*)d_in[9];
  const float* ncw2  = (const float*)d_in[10];
  const float* ncb2  = (const float*)d_in[11];
  const float* m0w1  = (const float*)d_in[12];
  const float* m0b1  = (const float*)d_in[13];
  const float* m0w2  = (const float*)d_in[14];
  const float* m0b2  = (const float*)d_in[15];
  const float* m1w1  = (const float*)d_in[16];
  const float* m1b1  = (const float*)d_in[17];
  const float* m1w2  = (const float*)d_in[18];
  const float* m1b2  = (const float*)d_in[19];
  const float* snw   = (const float*)d_in[20];
  const float* snb   = (const float*)d_in[21];
  char* ws = (char*)d_ws;

  k_init0  <<<65, 256, 0, stream>>>(ws, path);
  k_setupA <<<NCB + NEB + 1, 256, 0, stream>>>(ws, freep, collp, ei,
                                               ncw1, ncb1, m0w1, m0b1, ncw2, ncb2);
  k_scan2  <<<2, 256, 0, stream>>>(ws);
  k_scatter<<<NCB, 256, 0, stream>>>(ws);

  // all 5 smoothing iterations in ONE launch; path crosses iterations via
  // cache-bypass atomics, read-only data stays L2-hot, barrier never invalidates
  k_loop_fused2<<<PN, 256, 0, stream>>>(ws, ncw1, gamma, beta, ncw2, ncb2,
                                        m0w2, m0b2, m1w1, m1b1, m1w2, m1b2,
                                        snw, snb, (float*)d_out);
}

// Round 4
// 441.360 us; speedup vs baseline: 1.1238x; 1.1238x over previous
//
#include <hip/hip_runtime.h>
#include <stdint.h>

// Problem constants (fixed by setup_inputs)
#define PN     512
#define NFREE  50000
#define NCND   100000
#define NNODE  100512
#define NEDGE  300000
#define KK     10
#define NLOOP  5
#define EPSV   1e-5f

#define GRID   128
#define NCELL  (GRID*GRID)

// fixed spatial-hash bounds: candidates ~N(0,1); clamping keeps exactness
#define XMINF  (-6.f)
#define YMINF  (-6.f)
#define SPANF  12.f
#define IVCW   ((float)GRID / SPANF)

#define HSIZE  8192
#define HMASK  (HSIZE-1)
#define E0CAP  4096
#define EMPTYK 0xFFFFFFFFFFFFFFFFull

#define NCB    ((NCND+255)/256)    // 391
#define NEB    ((NEDGE+255)/256)   // 1172

// workspace layout (bytes) — ~2.7 MB
#define OFF_HASH    ((size_t)0)
#define OFF_CPOS    (OFF_HASH    + (size_t)HSIZE*8)
#define OFF_SCND    (OFF_CPOS    + 800000)               // float4/cand, cell-sorted
#define OFF_CSTART  (OFF_SCND    + 1600000)              // NCELL+1 ints
#define OFF_COFS    (OFF_CSTART  + 65600)
#define OFF_MOM     (OFF_COFS    + 65600)                // 10 floats (cand moments)
#define OFF_WCU     (OFF_MOM     + 64)
#define OFF_WCV     (OFF_WCU     + 4096)
#define OFF_BU      (OFF_WCV     + 4096)
#define OFF_BV      (OFF_BU      + 128)
#define OFF_CPATH   (OFF_BV      + 128)
#define OFF_CFREE   (OFF_CPATH   + 128)
#define OFF_CCOL    (OFF_CFREE   + 128)
#define OFF_PATH    (OFF_CCOL    + 128)                  // 16-aligned
#define OFF_E0S     (OFF_PATH    + 4096)
#define OFF_E0D     (OFF_E0S     + (size_t)E0CAP*4)
#define OFF_DEG0    (OFF_E0D     + (size_t)E0CAP*4)
#define OFF_E0C     (OFF_DEG0    + 2048)
#define OFF_E0START (OFF_E0C     + 64)                   // 513 ints (pad 2112)
#define OFF_E0OFS   (OFF_E0START + 2112)
#define OFF_E0CSRS  (OFF_E0OFS   + 2048)                 // E0CAP ints

// E0S/E0D are dead after k_scan2 — reuse for the fused persistent loop:
#define OFF_PATH2   OFF_E0S     // ping-pong path buffer
#define OFF_GBAR    OFF_E0D     // per-generation arrival counters [NLOOP]

#define WS_F(o)  ((float*)(ws + (o)))
#define WS_I(o)  ((int*)(ws + (o)))
#define WS_H(o)  ((unsigned long long*)(ws + (o)))

__device__ __forceinline__ bool lexless(float da, int ia, float db, int ib) {
  return (da < db) || (da == db && ia < ib);
}

__device__ __forceinline__ uint32_t hslot(unsigned long long key) {
  return (uint32_t)((key * 0x9E3779B97F4A7C15ull) >> 40) & HMASK;
}

// ---- cross-XCD path IO: RELAXED agent-scope atomics (sc0 sc1 bypass — go
// straight to the coherence point; emit NO cache-maintenance ops).
__device__ __forceinline__ float agl(const float* p) {
  unsigned v = __hip_atomic_load((const unsigned*)p, __ATOMIC_RELAXED,
                                 __HIP_MEMORY_SCOPE_AGENT);
  return __uint_as_float(v);
}
__device__ __forceinline__ void ags(float* p, float v) {
  __hip_atomic_store((unsigned*)p, __float_as_uint(v), __ATOMIC_RELAXED,
                     __HIP_MEMORY_SCOPE_AGENT);
}

// Grid barrier with ZERO ordering semantics — rounds 1/3 proved any
// release/acquire (or threadfence) at agent scope costs a per-arrival L2
// wb-invalidate (96MB refetch storm). Here: visibility of the 4KB path is
// carried by the bypass stores themselves; arrival only needs a vmcnt DRAIN
// (wait, not flush). Poll loads are bypass too (always read the coherence
// point). Compiler-only fences stop reordering; no cache ops are emitted.
__device__ __forceinline__ void gridbar_relaxed(int* arr, int gen) {
  __syncthreads();                       // drains vmcnt/lgkmcnt per wave
  if (threadIdx.x == 0) {
    asm volatile("s_waitcnt vmcnt(0) lgkmcnt(0)" ::: "memory");
    __hip_atomic_fetch_add(&arr[gen], 1, __ATOMIC_RELAXED,
                           __HIP_MEMORY_SCOPE_AGENT);
    while (__hip_atomic_load(&arr[gen], __ATOMIC_RELAXED,
                             __HIP_MEMORY_SCOPE_AGENT) < (int)gridDim.x)
      __builtin_amdgcn_s_sleep(16);
    asm volatile("" ::: "memory");       // no code; blocks compiler hoisting
  }
  __syncthreads();
}

// BN mean/rstd from analytic moments (cand moments in MOM + path moments pm*)
__device__ __forceinline__ void bn_from_moments(const char* ws,
    float w0, float w1, float cp, float clsF, float clsC,
    float pm0, float pm1, float pm00, float pm11, float pm01,
    float* meano, float* rstdo) {
  const float* M = (const float*)(ws + OFF_MOM);
  float sF0=M[0], sF1=M[1], sF00=M[2], sF11=M[3], sF01=M[4];
  float sC0=M[5], sC1=M[6], sC00=M[7], sC11=M[8], sC01=M[9];
  const float NC = (float)(NCND - NFREE);
  float sh  = w0*(sF0+sC0+pm0) + w1*(sF1+sC1+pm1)
            + (float)NFREE*clsF + NC*clsC + (float)PN*cp;
  float sh2 = w0*w0*(sF00+sC00+pm00) + w1*w1*(sF11+sC11+pm11)
            + 2.f*w0*w1*(sF01+sC01+pm01)
            + 2.f*w0*(clsF*sF0 + clsC*sC0 + cp*pm0)
            + 2.f*w1*(clsF*sF1 + clsC*sC1 + cp*pm1)
            + (float)NFREE*clsF*clsF + NC*clsC*clsC + (float)PN*cp*cp;
  float mean = sh  * (1.f / NNODE);
  float ex2  = sh2 * (1.f / NNODE);
  float var  = ex2 - mean * mean;
  *meano = mean;
  *rstdo = 1.0f / sqrtf(var + EPSV);
}

#define INSERT10(d2v, jv)                                                  \
  if (lexless((d2v), (jv), bd[9], bi[9])) {                                \
    bool placed = false;                                                   \
    _Pragma("unroll")                                                      \
    for (int k = 9; k > 0; k--) {                                          \
      bool shift = !placed && lexless((d2v), (jv), bd[k-1], bi[k-1]);      \
      bool here  = !placed && !shift;                                      \
      if (here)       { bd[k] = (d2v); bi[k] = (jv); placed = true; }      \
      else if (shift) { bd[k] = bd[k-1]; bi[k] = bi[k-1]; }                \
    }                                                                      \
    if (!placed) { bd[0] = (d2v); bi[0] = (jv); }                          \
  }

// wave top-10 pop-merge -> LDS slots [base..base+9] (lane r writes rank r)
#define WSTORE10(base) do {                                                \
    float cd[10]; int ci[10];                                              \
    _Pragma("unroll")                                                      \
    for (int k = 0; k < 10; k++) { cd[k] = bd[k]; ci[k] = bi[k]; }         \
    _Pragma("unroll")                                                      \
    for (int r = 0; r < 10; r++) {                                         \
      float md = cd[0]; int mi = ci[0];                                    \
      _Pragma("unroll")                                                    \
      for (int off = 32; off >= 1; off >>= 1) {                            \
        float od = __shfl_xor(md, off);                                    \
        int   oi = __shfl_xor(mi, off);                                    \
        if (lexless(od, oi, md, mi)) { md = od; mi = oi; }                 \
      }                                                                    \
      bool win = (cd[0] == md) && (ci[0] == mi);                           \
      if (win) {                                                           \
        _Pragma("unroll")                                                  \
        for (int k = 0; k < 9; k++) { cd[k] = cd[k+1]; ci[k] = ci[k+1]; }  \
        cd[9] = 3.4e38f; ci[9] = 0x7FFFFFFF;                               \
      }                                                                    \
      if (lane == r) { sD[(base)+r] = md; sI[(base)+r] = mi; }             \
    }                                                                      \
  } while (0)

// exact rank-merge of the 40 LDS entries -> sMD/sMI[0..9] (wave 0 only)
#define MERGE40() do {                                                     \
    float de = (lane < 40) ? sD[lane] : 3.4e38f;                           \
    int   ie = (lane < 40) ? sI[lane] : 0x7FFFFFFF;                        \
    int rank = 0;                                                          \
    for (int f = 0; f < 40; f++) {                                         \
      float df = sD[f]; int iff = sI[f];                                   \
      bool less = lexless(df, iff, de, ie) ||                              \
                  (df == de && iff == ie && f < lane);                     \
      rank += less ? 1 : 0;                                                \
    }                                                                      \
    if (lane < 40 && rank < 10) { sMD[rank] = de; sMI[rank] = ie; }        \
  } while (0)

// scan rows of box [xA..xB]x[yA..yB] with y % 4 == wv (4-wave split);
// each row is a contiguous scnd span, lanes stride it (coalesced).
#define SCAN_BOX4(xA, xB, yA, yB) do {                                     \
    for (int _y = (yA) + wv; _y <= (yB); _y += 4) {                        \
      int _s = cst[_y*GRID + (xA)], _e = cst[_y*GRID + (xB) + 1];          \
      for (int _t = _s + lane; _t < _e; _t += 64) {                        \
        float4 _q = scnd[_t];                                              \
        float _d2 = (psq + _q.z) - 2.f * fmaf(p1, _q.y, p0 * _q.x);        \
        int _j = __float_as_int(_q.w);                                     \
        INSERT10(_d2, _j);                                                 \
      }                                                                    \
    }                                                                      \
  } while (0)

// ---------------- setup kernels ----------------

__global__ __launch_bounds__(256) void k_init0(char* __restrict__ ws,
                                               const float* __restrict__ path_in) {
  unsigned i = blockIdx.x * 256u + threadIdx.x;       // grid = 65 → 16640 ids
  if (i < HSIZE)   WS_H(OFF_HASH)[i] = EMPTYK;
  if (i < NCELL+1) WS_I(OFF_CSTART)[i] = 0;
  if (i < 1024)    WS_F(OFF_PATH)[i] = path_in[i];
  if (i < 512)     WS_I(OFF_DEG0)[i] = 0;
  if (i < 16)      WS_F(OFF_MOM)[i] = 0.f;
  if (i == 0)      *WS_I(OFF_E0C) = 0;
}

// roles: b<NCB cand(pos/moments/hist) | b<NCB+NEB edge filter+dedup | last wprep
__global__ __launch_bounds__(256) void k_setupA(char* __restrict__ ws,
    const float* __restrict__ freep, const float* __restrict__ collp,
    const int* __restrict__ ei,
    const float* __restrict__ ncw1, const float* __restrict__ ncb1,
    const float* __restrict__ m0w1, const float* __restrict__ m0b1,
    const float* __restrict__ ncw2, const float* __restrict__ ncb2) {
  int b = blockIdx.x, tid = threadIdx.x;
  if (b < NCB) {
    __shared__ float s10[4][10];
    int j = b*256 + tid;
    bool valid = (j < NCND);
    float c0 = 0.f, c1 = 0.f;
    if (valid) {
      if (j < NFREE) { c0 = freep[2*j];          c1 = freep[2*j+1]; }
      else           { c0 = collp[2*(j-NFREE)];  c1 = collp[2*(j-NFREE)+1]; }
      ((float2*)(ws + OFF_CPOS))[j] = make_float2(c0, c1);
    }
    bool isF = valid && (j < NFREE), isC = valid && (j >= NFREE);
    float v[10];
    v[0]=isF?c0:0.f; v[1]=isF?c1:0.f; v[2]=isF?c0*c0:0.f; v[3]=isF?c1*c1:0.f; v[4]=isF?c0*c1:0.f;
    v[5]=isC?c0:0.f; v[6]=isC?c1:0.f; v[7]=isC?c0*c0:0.f; v[8]=isC?c1*c1:0.f; v[9]=isC?c0*c1:0.f;
    #pragma unroll
    for (int q = 0; q < 10; q++)
      #pragma unroll
      for (int off = 32; off >= 1; off >>= 1) v[q] += __shfl_xor(v[q], off);
    int wv = tid >> 6, lane = tid & 63;
    if (lane == 0) {
      #pragma unroll
      for (int q = 0; q < 10; q++) s10[wv][q] = v[q];
    }
    if (valid) {
      int cx = min(GRID-1, max(0, (int)((c0 - XMINF) * IVCW)));
      int cy = min(GRID-1, max(0, (int)((c1 - YMINF) * IVCW)));
      atomicAdd(&WS_I(OFF_CSTART)[cy*GRID + cx], 1);
    }
    __syncthreads();
    if (tid < 10)
      atomicAdd(&WS_F(OFF_MOM)[tid], s10[0][tid]+s10[1][tid]+s10[2][tid]+s10[3][tid]);
  } else if (b < NCB + NEB) {
    int e = (b - NCB)*256 + tid;
    if (e >= NEDGE) return;
    int src = ei[e], dst = ei[NEDGE + e];
    if (dst >= PN) return;                         // only dst<PN edges matter
    unsigned long long key = (unsigned long long)src * NNODE + (unsigned long long)dst;
    unsigned long long* hash = WS_H(OFF_HASH);
    uint32_t slot = hslot(key);
    for (;;) {
      unsigned long long prev = atomicCAS(&hash[slot], EMPTYK, key);
      if (prev == EMPTYK) {
        int pos = atomicAdd(WS_I(OFF_E0C), 1);
        if (pos < E0CAP) {
          WS_I(OFF_E0S)[pos] = src;
          WS_I(OFF_E0D)[pos] = dst;
          atomicAdd(&WS_I(OFF_DEG0)[dst], 1);
        }
        break;
      }
      if (prev == key) break;
      slot = (slot + 1) & HMASK;
    }
  } else {
    __shared__ float Wu[1024], Wv[1024];
    for (int it = 0; it < 4; it++) {
      int idx = it*256 + tid, k = idx >> 5, g = idx & 31;
      float a = m0w1[k*32+g], b2 = m0w1[(k+32)*32+g], c = m0w1[(k+64)*32+g];
      Wu[idx] = a + b2;  Wv[idx] = c - a;
    }
    __syncthreads();
    for (int it = 0; it < 4; it++) {
      int idx = it*256 + tid, k = idx >> 5, g = idx & 31;
      float au = 0.f, av = 0.f;
      #pragma unroll
      for (int f = 0; f < 32; f++) {
        float w2 = ncw2[k*32+f];
        au = fmaf(w2, Wu[f*32+g], au);
        av = fmaf(w2, Wv[f*32+g], av);
      }
      WS_F(OFF_WCU)[idx] = au;  WS_F(OFF_WCV)[idx] = av;
    }
    if (tid < 32) {
      float bu = 0.f, bv = 0.f;
      #pragma unroll
      for (int f = 0; f < 32; f++) {
        bu = fmaf(ncb2[f], Wu[f*32+tid], bu);
        bv = fmaf(ncb2[f], Wv[f*32+tid], bv);
      }
      WS_F(OFF_BU)[tid] = bu;
      WS_F(OFF_BV)[tid] = bv + m0b1[tid];        // fold mp0_b1 into dst-side
      WS_F(OFF_CPATH)[tid] = ncw1[64+tid]  + ncb1[tid];
      WS_F(OFF_CFREE)[tid] = ncw1[96+tid]  + ncb1[tid];
      WS_F(OFF_CCOL)[tid]  = ncw1[128+tid] + ncb1[tid];
    }
  }
}

// b==0: exclusive scan of cell counts | b==1: CSR build of fixed edges
__global__ __launch_bounds__(256) void k_scan2(char* __restrict__ ws) {
  int b = blockIdx.x, tid = threadIdx.x;
  if (b == 0) {
    __shared__ int part[256];
    int* cnt = WS_I(OFF_CSTART);
    int base = tid * (NCELL/256);
    int sum = 0;
    for (int k = 0; k < NCELL/256; k++) sum += cnt[base+k];
    part[tid] = sum;
    __syncthreads();
    for (int off = 1; off < 256; off <<= 1) {
      int t = (tid >= off) ? part[tid - off] : 0;
      __syncthreads();
      part[tid] += t;
      __syncthreads();
    }
    int run = part[tid] - sum;
    for (int k = 0; k < NCELL/256; k++) {
      int c = cnt[base+k];
      cnt[base+k] = run;
      WS_I(OFF_COFS)[base+k] = run;
      run += c;
    }
    if (tid == 255) cnt[NCELL] = run;
  } else {
    __shared__ int sc[512];
    sc[tid]     = WS_I(OFF_DEG0)[tid];
    sc[256+tid] = WS_I(OFF_DEG0)[256+tid];
    __syncthreads();
    if (tid == 0) {
      int run = 0;
      for (int i = 0; i < 512; i++) { int c = sc[i]; sc[i] = run; run += c; }
      WS_I(OFF_E0START)[512] = run;
    }
    __syncthreads();
    WS_I(OFF_E0START)[tid]     = sc[tid];
    WS_I(OFF_E0START)[256+tid] = sc[256+tid];
    WS_I(OFF_E0OFS)[tid]       = sc[tid];
    WS_I(OFF_E0OFS)[256+tid]   = sc[256+tid];
    __syncthreads();
    int n = *WS_I(OFF_E0C); if (n > E0CAP) n = E0CAP;
    for (int e = tid; e < n; e += 256) {
      int dst = WS_I(OFF_E0D)[e];
      int pos = atomicAdd(&WS_I(OFF_E0OFS)[dst], 1);
      WS_I(OFF_E0CSRS)[pos] = WS_I(OFF_E0S)[e];
    }
  }
}

__global__ __launch_bounds__(256) void k_scatter(char* __restrict__ ws) {
  // E0D is dead after k_scan2; zero the generation counters that alias it.
  if (blockIdx.x == 0 && threadIdx.x < NLOOP) WS_I(OFF_GBAR)[threadIdx.x] = 0;
  int j = blockIdx.x * 256 + threadIdx.x;
  if (j >= NCND) return;
  float2 c = ((const float2*)(ws + OFF_CPOS))[j];
  int cx = min(GRID-1, max(0, (int)((c.x - XMINF) * IVCW)));
  int cy = min(GRID-1, max(0, (int)((c.y - YMINF) * IVCW)));
  int pos = atomicAdd(&WS_I(OFF_COFS)[cy*GRID + cx], 1);
  ((float4*)(ws + OFF_SCND))[pos] =
      make_float4(c.x, c.y, c.x*c.x + c.y*c.y, __int_as_float(j));
}

// ---------------- fused persistent per-loop kernel, take 3 ----------------
// Same per-iteration body as the verified 5-dispatch k_loop_v2 (absmax 0.0),
// wrapped in an in-kernel loop with the ordering-free barrier. Path crosses
// iterations via bypass atomics only; read-only data stays L2-hot (no flush).
__global__ __launch_bounds__(256, 2) void k_loop_fused3(char* __restrict__ ws,
    const float* __restrict__ ncw1, const float* __restrict__ gamma,
    const float* __restrict__ beta, const float* __restrict__ ncw2,
    const float* __restrict__ ncb2, const float* __restrict__ m0w2,
    const float* __restrict__ m0b2, const float* __restrict__ m1w1,
    const float* __restrict__ m1b1, const float* __restrict__ m1w2,
    const float* __restrict__ m1b2, const float* __restrict__ snw,
    const float* __restrict__ snb, float* __restrict__ outp) {
  __shared__ float sD[40];
  __shared__ int   sI[40];
  __shared__ float sMD[10];
  __shared__ int   sMI[10];
  __shared__ int   sbox[9];           // xL,xR,yL,yR, xL2,xR2,yL2,yR2, skip
  __shared__ int   sRC[4];            // per-wave phase-A counts
  __shared__ float sS[4][32];         // per-wave partial S
  int tid = threadIdx.x, lane = tid & 63, wv = tid >> 6;
  int node = blockIdx.x;
  const float4* scnd = (const float4*)(ws + OFF_SCND);
  const int* cst = WS_I(OFF_CSTART);
  int* bar = WS_I(OFF_GBAR);

  // loop-invariant per-lane state (read-only, cached)
  int fA = lane & 31;
  const float w0 = ncw1[fA], w1 = ncw1[32+fA];
  const float cp   = WS_F(OFF_CPATH)[fA];
  const float clsF = WS_F(OFF_CFREE)[fA];
  const float clsC = WS_F(OFF_CCOL)[fA];
  const float gm = gamma[fA], bt = beta[fA];
  const float buf = WS_F(OFF_BU)[fA];
  const float bvf = WS_F(OFF_BV)[fA];
  const float* wcu = WS_F(OFF_WCU);
  const float* wcv = WS_F(OFF_WCV);
  const int s0 = WS_I(OFF_E0START)[node], s1 = WS_I(OFF_E0START)[node+1];
  const int nfix = s1 - s0;
  const int fsrc = (lane < nfix) ? WS_I(OFF_E0CSRS)[s0 + lane] : -1;

  for (int l = 0; l < NLOOP; ++l) {
    float* pcur = WS_F((l & 1) ? OFF_PATH2 : OFF_PATH);
    float* pnxt = WS_F((l & 1) ? OFF_PATH  : OFF_PATH2);
    float p0 = agl(&pcur[2*node]), p1 = agl(&pcur[2*node+1]);
    float psq = p0*p0 + p1*p1;

    // ---- phase A: probe R = 1<<wv in parallel (one radius per wave) ----
    int cx = min(GRID-1, max(0, (int)((p0 - XMINF) * IVCW)));
    int cy = min(GRID-1, max(0, (int)((p1 - YMINF) * IVCW)));
    {
      int Rw = 1 << wv;
      int xA = max(cx-Rw, 0), xB = min(cx+Rw, GRID-1);
      int yA = max(cy-Rw, 0), yB = min(cy+Rw, GRID-1);
      int cnt = 0;
      for (int y = yA + lane; y <= yB; y += 64)
        cnt += cst[y*GRID + xB + 1] - cst[y*GRID + xA];
      #pragma unroll
      for (int off = 32; off >= 1; off >>= 1) cnt += __shfl_xor(cnt, off);
      if (lane == 0) sRC[wv] = cnt;
    }
    __syncthreads();
    if (wv == 0) {
      int R = 0;
      if (sRC[3] >= KK) R = 8;
      if (sRC[2] >= KK) R = 4;
      if (sRC[1] >= KK) R = 2;
      if (sRC[0] >= KK) R = 1;
      int xLa, xRa, yLa, yRa;
      if (R == 0) {                       // rare sparse-region fallback
        R = 16;
        for (;;) {
          xLa = max(cx-R, 0); xRa = min(cx+R, GRID-1);
          yLa = max(cy-R, 0); yRa = min(cy+R, GRID-1);
          int cnt = 0;
          for (int y = yLa + lane; y <= yRa; y += 64)
            cnt += cst[y*GRID + xRa + 1] - cst[y*GRID + xLa];
          #pragma unroll
          for (int off = 32; off >= 1; off >>= 1) cnt += __shfl_xor(cnt, off);
          if (cnt >= KK || R >= GRID) break;
          R <<= 1;
        }
      } else {
        xLa = max(cx-R, 0); xRa = min(cx+R, GRID-1);
        yLa = max(cy-R, 0); yRa = min(cy+R, GRID-1);
      }
      if (lane == 0) { sbox[0]=xLa; sbox[1]=xRa; sbox[2]=yLa; sbox[3]=yRa; }
    }
    __syncthreads();
    int xL = sbox[0], xR = sbox[1], yL = sbox[2], yR = sbox[3];

    // ---- phase B: 4-wave split scan of seed box ----
    float bd[10]; int bi[10];
    #pragma unroll
    for (int k = 0; k < 10; k++) { bd[k] = 3.4e38f; bi[k] = 0x7FFFFFFF; }
    SCAN_BOX4(xL, xR, yL, yR);
    WSTORE10(wv*10);
    __syncthreads();
    if (wv == 0) MERGE40();
    __syncthreads();

    // ---- phase C box + containment test (skip if seed scan already exact) --
    if (tid == 0) {
      float r = sqrtf(sMD[9]) * 1.000002f;
      int xL2 = min(GRID-1, max(0, (int)((p0 - r - XMINF) * IVCW)));
      int xR2 = min(GRID-1, max(0, (int)((p0 + r - XMINF) * IVCW)));
      int yL2 = min(GRID-1, max(0, (int)((p1 - r - YMINF) * IVCW)));
      int yR2 = min(GRID-1, max(0, (int)((p1 + r - YMINF) * IVCW)));
      sbox[4]=xL2; sbox[5]=xR2; sbox[6]=yL2; sbox[7]=yR2;
      sbox[8] = (xL2 >= xL && xR2 <= xR && yL2 >= yL && yR2 <= yR) ? 1 : 0;
    }
    __syncthreads();
    if (!sbox[8]) {
      int xL2 = sbox[4], xR2 = sbox[5], yL2 = sbox[6], yR2 = sbox[7];
      #pragma unroll
      for (int k = 0; k < 10; k++) { bd[k] = 3.4e38f; bi[k] = 0x7FFFFFFF; }
      SCAN_BOX4(xL2, xR2, yL2, yR2);
      WSTORE10(wv*10);
      __syncthreads();
      if (wv == 0) MERGE40();
      __syncthreads();
    }

    // ======== all 4 waves work from here ========

    // dedup kNN vs fixed edges — pure register shfl
    int selIdx = (lane < KK) ? sMI[lane] : 0;
    int srcg   = (lane < KK) ? selIdx + PN : -1;
    int keep   = (lane < KK) ? 1 : 0;
    for (int t = 0; t < min(nfix, 64); t++) {
      int fs = __shfl(fsrc, t);
      if (fs == srcg) keep = 0;
    }
    for (int t = 64; t < nfix; t++) {            // ~never
      int fs = WS_I(OFF_E0CSRS)[s0 + t];
      if (fs == srcg) keep = 0;
    }
    unsigned long long kmask = __ballot(keep);
    int deg = (int)__popcll(kmask) + nfix;

    // parallel prefetch of per-edge data: lane e holds edge e
    int t2 = lane - KK;
    int srcb = __shfl(fsrc, (t2 & 63));          // uniform-exec shfl
    float eq0 = 0.f, eq1 = 0.f; int ecl = 1, eva = 0;
    if (lane < KK) {
      eva = keep;
      if (keep) {
        eq0 = WS_F(OFF_CPOS)[2*selIdx];
        eq1 = WS_F(OFF_CPOS)[2*selIdx+1];
        ecl = (selIdx < NFREE) ? 1 : 2;
      }
    } else if (t2 < nfix) {                      // t2 <= 53 always
      eva = 1;
      if (srcb < PN) { eq0 = agl(&pcur[2*srcb]); eq1 = agl(&pcur[2*srcb+1]); ecl = 0; }
      else {
        int jj = srcb - PN;
        eq0 = WS_F(OFF_CPOS)[2*jj]; eq1 = WS_F(OFF_CPOS)[2*jj+1];
        ecl = (jj < NFREE) ? 1 : 2;
      }
    }

    // BN path moments — identical per-wave order to the verified k_loop_v2
    float pm0=0,pm1=0,pm00=0,pm11=0,pm01=0;
    for (int r2 = lane; r2 < PN; r2 += 64) {
      float qx = agl(&pcur[2*r2]), qy = agl(&pcur[2*r2+1]);
      pm0+=qx; pm1+=qy; pm00+=qx*qx; pm11+=qy*qy; pm01+=qx*qy;
    }
    #pragma unroll
    for (int off = 32; off >= 1; off >>= 1) {
      pm0+=__shfl_xor(pm0,off); pm1+=__shfl_xor(pm1,off); pm00+=__shfl_xor(pm00,off);
      pm11+=__shfl_xor(pm11,off); pm01+=__shfl_xor(pm01,off);
    }
    float mean, rstd;
    bn_from_moments(ws, w0, w1, cp, clsF, clsC, pm0, pm1, pm00, pm11, pm01,
                    &mean, &rstd);

    // xn_dst and v[dst] (per wave)
    float hD = fmaf(p1, w1, fmaf(p0, w0, cp));
    float xnd = fmaf((hD - mean) * rstd, gm, bt);
    xnd = xnd > 0.f ? xnd : 0.f;
    float av = bvf;
    #pragma unroll
    for (int m = 0; m < 32; m++) av = fmaf(__shfl(xnd, m), wcv[m*32+fA], av);

    // S over edges: 8-way parallel (4 waves x 2 half-waves), uniform trips
    int hf = lane >> 5;
    int Etot = KK + min(nfix, 54);
    int nT = (Etot + 7) >> 3;
    float S = 0.f;
    for (int t = 0; t < nT; t++) {
      int e  = (t << 3) + (wv << 1) + hf;
      int ee = e & 63;
      int   ev = __shfl(eva, ee);
      float q0 = __shfl(eq0, ee), q1 = __shfl(eq1, ee);
      int   ec = __shfl(ecl, ee);
      float clsv = (ec == 0) ? cp : ((ec == 1) ? clsF : clsC);
      float hq = fmaf(q1, w1, fmaf(q0, w0, clsv));
      float xnf = fmaf((hq - mean) * rstd, gm, bt);
      xnf = xnf > 0.f ? xnf : 0.f;
      float au = buf;
      #pragma unroll
      for (int m = 0; m < 32; m++)
        au = fmaf(__shfl(xnf, m, 32), wcu[m*32+fA], au);
      float rr = au + av;
      if (e < Etot && ev && rr > 0.f) S += rr;
    }
    S += __shfl_xor(S, 32);                      // combine half-waves
    if (lane < 32) sS[wv][lane] = S;
    __syncthreads();

    if (wv == 0) {
      float St = sS[0][fA] + sS[1][fA] + sS[2][fA] + sS[3][fA];
      for (int t = 54; t < nfix; t++) {          // ~never: overflow tail
        int src = WS_I(OFF_E0CSRS)[s0 + t];
        float q0, q1, clsv;
        if (src < PN) { q0 = agl(&pcur[2*src]); q1 = agl(&pcur[2*src+1]); clsv = cp; }
        else {
          int jj = src - PN;
          q0 = WS_F(OFF_CPOS)[2*jj]; q1 = WS_F(OFF_CPOS)[2*jj+1];
          clsv = (jj < NFREE) ? clsF : clsC;
        }
        float hq = fmaf(q1, w1, fmaf(q0, w0, clsv));
        float xnf = fmaf((hq - mean) * rstd, gm, bt);
        xnf = xnf > 0.f ? xnf : 0.f;
        float au = buf;
        #pragma unroll
        for (int m = 0; m < 32; m++) au = fmaf(__shfl(xnf, m), wcu[m*32+fA], au);
        float rr = au + av;
        if (rr > 0.f) St += rr;
      }

      // epilogue: four 32x32 GEMVs via shfl-dots
      float o = (float)deg * m0b2[fA];
      #pragma unroll
      for (int k = 0; k < 32; k++) o = fmaf(__shfl(St, k), m0w2[k*32+fA], o);
      float t1 = m1b1[fA];
      #pragma unroll
      for (int k = 0; k < 32; k++) t1 = fmaf(__shfl(o, k), m1w1[k*32+fA], t1);
      t1 = t1 > 0.f ? t1 : 0.f;
      float g2 = m1b2[fA];
      #pragma unroll
      for (int k = 0; k < 32; k++) g2 = fmaf(__shfl(t1, k), m1w2[k*32+fA], g2);
      float x = ncb2[fA];
      #pragma unroll
      for (int k = 0; k < 32; k++) x = fmaf(__shfl(xnd, k), ncw2[k*32+fA], x);
      float hh = x + g2;
      float r0 = hh * snw[2*fA], r1 = hh * snw[2*fA+1];
      #pragma unroll
      for (int off = 16; off >= 1; off >>= 1) {
        r0 += __shfl_xor(r0, off);
        r1 += __shfl_xor(r1, off);
      }
      if (lane == 0) {
        float np0, np1;
        if (node == 0 || node == PN-1) { np0 = p0; np1 = p1; }  // endpoints fixed
        else { np0 = snb[0] + r0; np1 = snb[1] + r1; }
        if (l == NLOOP-1) { outp[2*node] = np0; outp[2*node+1] = np1; }
        else { ags(&pnxt[2*node], np0); ags(&pnxt[2*node+1], np1); }
      }
    }

    if (l < NLOOP-1) gridbar_relaxed(bar, l);
  }
}

// ---------------- host launch ----------------

extern "C" void kernel_launch(void* const* d_in, const int* in_sizes, int n_in,
                              void* d_out, int out_size, void* d_ws, size_t ws_size,
                              hipStream_t stream) {
  const float* path  = (const float*)d_in[0];
  const float* freep = (const float*)d_in[1];
  const float* collp = (const float*)d_in[2];
  const int*   ei    = (const int*)d_in[4];
  const float* ncw1  = (const float*)d_in[6];
  const float* ncb1  = (const float*)d_in[7];
  const float* gamma = (const float*)d_in[8];
  const float* beta  = (const float*)d_in[9];
  const float* ncw2  = (const float*)d_in[10];
  const float* ncb2  = (const float*)d_in[11];
  const float* m0w1  = (const float*)d_in[12];
  const float* m0b1  = (const float*)d_in[13];
  const float* m0w2  = (const float*)d_in[14];
  const float* m0b2  = (const float*)d_in[15];
  const float* m1w1  = (const float*)d_in[16];
  const float* m1b1  = (const float*)d_in[17];
  const float* m1w2  = (const float*)d_in[18];
  const float* m1b2  = (const float*)d_in[19];
  const float* snw   = (const float*)d_in[20];
  const float* snb   = (const float*)d_in[21];
  char* ws = (char*)d_ws;

  k_init0  <<<65, 256, 0, stream>>>(ws, path);
  k_setupA <<<NCB + NEB + 1, 256, 0, stream>>>(ws, freep, collp, ei,
                                               ncw1, ncb1, m0w1, m0b1, ncw2, ncb2);
  k_scan2  <<<2, 256, 0, stream>>>(ws);
  k_scatter<<<NCB, 256, 0, stream>>>(ws);

  // all 5 smoothing iterations in ONE launch; ordering-free barrier keeps
  // the read-only working set L2-hot across iterations (no wb-inv storms)
  k_loop_fused3<<<PN, 256, 0, stream>>>(ws, ncw1, gamma, beta, ncw2, ncb2,
                                        m0w2, m0b2, m1w1, m1b1, m1w2, m1b2,
                                        snw, snb, (float*)d_out);
}

// Round 5
// 265.400 us; speedup vs baseline: 1.8689x; 1.6630x over previous
//
#include <hip/hip_runtime.h>
#include <stdint.h>

// Problem constants (fixed by setup_inputs)
#define PN     512
#define NFREE  50000
#define NCND   100000
#define NNODE  100512
#define NEDGE  300000
#define KK     10
#define NLOOP  5
#define EPSV   1e-5f

#define GRID   128
#define NCELL  (GRID*GRID)

// fixed spatial-hash bounds: candidates ~N(0,1); clamping keeps exactness
#define XMINF  (-6.f)
#define YMINF  (-6.f)
#define SPANF  12.f
#define IVCW   ((float)GRID / SPANF)

#define HSIZE  8192
#define HMASK  (HSIZE-1)
#define E0CAP  4096
#define EMPTYK 0xFFFFFFFFFFFFFFFFull

#define NCB    ((NCND+255)/256)    // 391
#define NEB    ((NEDGE+255)/256)   // 1172

// workspace layout (bytes) — ~2.7 MB
#define OFF_HASH    ((size_t)0)
#define OFF_CPOS    (OFF_HASH    + (size_t)HSIZE*8)
#define OFF_SCND    (OFF_CPOS    + 800000)               // float4/cand, cell-sorted
#define OFF_CSTART  (OFF_SCND    + 1600000)              // NCELL+1 ints
#define OFF_COFS    (OFF_CSTART  + 65600)
#define OFF_MOM     (OFF_COFS    + 65600)                // 10 floats (cand moments)
#define OFF_WCU     (OFF_MOM     + 64)
#define OFF_WCV     (OFF_WCU     + 4096)
#define OFF_BU      (OFF_WCV     + 4096)
#define OFF_BV      (OFF_BU      + 128)
#define OFF_CPATH   (OFF_BV      + 128)
#define OFF_CFREE   (OFF_CPATH   + 128)
#define OFF_CCOL    (OFF_CFREE   + 128)
#define OFF_PATH    (OFF_CCOL    + 128)                  // 16-aligned
#define OFF_E0S     (OFF_PATH    + 4096)
#define OFF_E0D     (OFF_E0S     + (size_t)E0CAP*4)
#define OFF_DEG0    (OFF_E0D     + (size_t)E0CAP*4)
#define OFF_E0C     (OFF_DEG0    + 2048)
#define OFF_E0START (OFF_E0C     + 64)                   // 513 ints (pad 2112)
#define OFF_E0OFS   (OFF_E0START + 2112)
#define OFF_E0CSRS  (OFF_E0OFS   + 2048)                 // E0CAP ints

// E0S is dead after k_scan2 — reuse as the ping-pong path buffer.
#define OFF_PATH2   OFF_E0S

#define WS_F(o)  ((float*)(ws + (o)))
#define WS_I(o)  ((int*)(ws + (o)))
#define WS_H(o)  ((unsigned long long*)(ws + (o)))

__device__ __forceinline__ bool lexless(float da, int ia, float db, int ib) {
  return (da < db) || (da == db && ia < ib);
}

__device__ __forceinline__ uint32_t hslot(unsigned long long key) {
  return (uint32_t)((key * 0x9E3779B97F4A7C15ull) >> 40) & HMASK;
}

// BN mean/rstd from analytic moments (cand moments in MOM + path moments pm*)
__device__ __forceinline__ void bn_from_moments(const char* ws,
    float w0, float w1, float cp, float clsF, float clsC,
    float pm0, float pm1, float pm00, float pm11, float pm01,
    float* meano, float* rstdo) {
  const float* M = (const float*)(ws + OFF_MOM);
  float sF0=M[0], sF1=M[1], sF00=M[2], sF11=M[3], sF01=M[4];
  float sC0=M[5], sC1=M[6], sC00=M[7], sC11=M[8], sC01=M[9];
  const float NC = (float)(NCND - NFREE);
  float sh  = w0*(sF0+sC0+pm0) + w1*(sF1+sC1+pm1)
            + (float)NFREE*clsF + NC*clsC + (float)PN*cp;
  float sh2 = w0*w0*(sF00+sC00+pm00) + w1*w1*(sF11+sC11+pm11)
            + 2.f*w0*w1*(sF01+sC01+pm01)
            + 2.f*w0*(clsF*sF0 + clsC*sC0 + cp*pm0)
            + 2.f*w1*(clsF*sF1 + clsC*sC1 + cp*pm1)
            + (float)NFREE*clsF*clsF + NC*clsC*clsC + (float)PN*cp*cp;
  float mean = sh  * (1.f / NNODE);
  float ex2  = sh2 * (1.f / NNODE);
  float var  = ex2 - mean * mean;
  *meano = mean;
  *rstdo = 1.0f / sqrtf(var + EPSV);
}

#define INSERT10(d2v, jv)                                                  \
  if (lexless((d2v), (jv), bd[9], bi[9])) {                                \
    bool placed = false;                                                   \
    _Pragma("unroll")                                                      \
    for (int k = 9; k > 0; k--) {                                          \
      bool shift = !placed && lexless((d2v), (jv), bd[k-1], bi[k-1]);      \
      bool here  = !placed && !shift;                                      \
      if (here)       { bd[k] = (d2v); bi[k] = (jv); placed = true; }      \
      else if (shift) { bd[k] = bd[k-1]; bi[k] = bi[k-1]; }                \
    }                                                                      \
    if (!placed) { bd[0] = (d2v); bi[0] = (jv); }                          \
  }

// wave top-10 pop-merge -> LDS slots [base..base+9] (lane r writes rank r)
#define WSTORE10(base) do {                                                \
    float cd[10]; int ci[10];                                              \
    _Pragma("unroll")                                                      \
    for (int k = 0; k < 10; k++) { cd[k] = bd[k]; ci[k] = bi[k]; }         \
    _Pragma("unroll")                                                      \
    for (int r = 0; r < 10; r++) {                                         \
      float md = cd[0]; int mi = ci[0];                                    \
      _Pragma("unroll")                                                    \
      for (int off = 32; off >= 1; off >>= 1) {                            \
        float od = __shfl_xor(md, off);                                    \
        int   oi = __shfl_xor(mi, off);                                    \
        if (lexless(od, oi, md, mi)) { md = od; mi = oi; }                 \
      }                                                                    \
      bool win = (cd[0] == md) && (ci[0] == mi);                           \
      if (win) {                                                           \
        _Pragma("unroll")                                                  \
        for (int k = 0; k < 9; k++) { cd[k] = cd[k+1]; ci[k] = ci[k+1]; }  \
        cd[9] = 3.4e38f; ci[9] = 0x7FFFFFFF;                               \
      }                                                                    \
      if (lane == r) { sD[(base)+r] = md; sI[(base)+r] = mi; }             \
    }                                                                      \
  } while (0)

// exact rank-merge of the 40 LDS entries -> sMD/sMI[0..9] (wave 0 only)
#define MERGE40() do {                                                     \
    float de = (lane < 40) ? sD[lane] : 3.4e38f;                           \
    int   ie = (lane < 40) ? sI[lane] : 0x7FFFFFFF;                        \
    int rank = 0;                                                          \
    for (int f = 0; f < 40; f++) {                                         \
      float df = sD[f]; int iff = sI[f];                                   \
      bool less = lexless(df, iff, de, ie) ||                              \
                  (df == de && iff == ie && f < lane);                     \
      rank += less ? 1 : 0;                                                \
    }                                                                      \
    if (lane < 40 && rank < 10) { sMD[rank] = de; sMI[rank] = ie; }        \
  } while (0)

// scan rows of box [xA..xB]x[yA..yB] with y % 4 == wv (4-wave split);
// each row is a contiguous scnd span, lanes stride it (coalesced).
#define SCAN_BOX4(xA, xB, yA, yB) do {                                     \
    for (int _y = (yA) + wv; _y <= (yB); _y += 4) {                        \
      int _s = cst[_y*GRID + (xA)], _e = cst[_y*GRID + (xB) + 1];          \
      for (int _t = _s + lane; _t < _e; _t += 64) {                        \
        float4 _q = scnd[_t];                                              \
        float _d2 = (psq + _q.z) - 2.f * fmaf(p1, _q.y, p0 * _q.x);        \
        int _j = __float_as_int(_q.w);                                     \
        INSERT10(_d2, _j);                                                 \
      }                                                                    \
    }                                                                      \
  } while (0)

// ---------------- setup kernels ----------------

__global__ __launch_bounds__(256) void k_init0(char* __restrict__ ws,
                                               const float* __restrict__ path_in) {
  unsigned i = blockIdx.x * 256u + threadIdx.x;       // grid = 65 → 16640 ids
  if (i < HSIZE)   WS_H(OFF_HASH)[i] = EMPTYK;
  if (i < NCELL+1) WS_I(OFF_CSTART)[i] = 0;
  if (i < 1024)    WS_F(OFF_PATH)[i] = path_in[i];
  if (i < 512)     WS_I(OFF_DEG0)[i] = 0;
  if (i < 16)      WS_F(OFF_MOM)[i] = 0.f;
  if (i == 0)      *WS_I(OFF_E0C) = 0;
}

// roles: b<NCB cand(pos/moments/hist) | b<NCB+NEB edge filter+dedup | last wprep
__global__ __launch_bounds__(256) void k_setupA(char* __restrict__ ws,
    const float* __restrict__ freep, const float* __restrict__ collp,
    const int* __restrict__ ei,
    const float* __restrict__ ncw1, const float* __restrict__ ncb1,
    const float* __restrict__ m0w1, const float* __restrict__ m0b1,
    const float* __restrict__ ncw2, const float* __restrict__ ncb2) {
  int b = blockIdx.x, tid = threadIdx.x;
  if (b < NCB) {
    __shared__ float s10[4][10];
    int j = b*256 + tid;
    bool valid = (j < NCND);
    float c0 = 0.f, c1 = 0.f;
    if (valid) {
      if (j < NFREE) { c0 = freep[2*j];          c1 = freep[2*j+1]; }
      else           { c0 = collp[2*(j-NFREE)];  c1 = collp[2*(j-NFREE)+1]; }
      ((float2*)(ws + OFF_CPOS))[j] = make_float2(c0, c1);
    }
    bool isF = valid && (j < NFREE), isC = valid && (j >= NFREE);
    float v[10];
    v[0]=isF?c0:0.f; v[1]=isF?c1:0.f; v[2]=isF?c0*c0:0.f; v[3]=isF?c1*c1:0.f; v[4]=isF?c0*c1:0.f;
    v[5]=isC?c0:0.f; v[6]=isC?c1:0.f; v[7]=isC?c0*c0:0.f; v[8]=isC?c1*c1:0.f; v[9]=isC?c0*c1:0.f;
    #pragma unroll
    for (int q = 0; q < 10; q++)
      #pragma unroll
      for (int off = 32; off >= 1; off >>= 1) v[q] += __shfl_xor(v[q], off);
    int wv = tid >> 6, lane = tid & 63;
    if (lane == 0) {
      #pragma unroll
      for (int q = 0; q < 10; q++) s10[wv][q] = v[q];
    }
    if (valid) {
      int cx = min(GRID-1, max(0, (int)((c0 - XMINF) * IVCW)));
      int cy = min(GRID-1, max(0, (int)((c1 - YMINF) * IVCW)));
      atomicAdd(&WS_I(OFF_CSTART)[cy*GRID + cx], 1);
    }
    __syncthreads();
    if (tid < 10)
      atomicAdd(&WS_F(OFF_MOM)[tid], s10[0][tid]+s10[1][tid]+s10[2][tid]+s10[3][tid]);
  } else if (b < NCB + NEB) {
    int e = (b - NCB)*256 + tid;
    if (e >= NEDGE) return;
    int src = ei[e], dst = ei[NEDGE + e];
    if (dst >= PN) return;                         // only dst<PN edges matter
    unsigned long long key = (unsigned long long)src * NNODE + (unsigned long long)dst;
    unsigned long long* hash = WS_H(OFF_HASH);
    uint32_t slot = hslot(key);
    for (;;) {
      unsigned long long prev = atomicCAS(&hash[slot], EMPTYK, key);
      if (prev == EMPTYK) {
        int pos = atomicAdd(WS_I(OFF_E0C), 1);
        if (pos < E0CAP) {
          WS_I(OFF_E0S)[pos] = src;
          WS_I(OFF_E0D)[pos] = dst;
          atomicAdd(&WS_I(OFF_DEG0)[dst], 1);
        }
        break;
      }
      if (prev == key) break;
      slot = (slot + 1) & HMASK;
    }
  } else {
    __shared__ float Wu[1024], Wv[1024];
    for (int it = 0; it < 4; it++) {
      int idx = it*256 + tid, k = idx >> 5, g = idx & 31;
      float a = m0w1[k*32+g], b2 = m0w1[(k+32)*32+g], c = m0w1[(k+64)*32+g];
      Wu[idx] = a + b2;  Wv[idx] = c - a;
    }
    __syncthreads();
    for (int it = 0; it < 4; it++) {
      int idx = it*256 + tid, k = idx >> 5, g = idx & 31;
      float au = 0.f, av = 0.f;
      #pragma unroll
      for (int f = 0; f < 32; f++) {
        float w2 = ncw2[k*32+f];
        au = fmaf(w2, Wu[f*32+g], au);
        av = fmaf(w2, Wv[f*32+g], av);
      }
      WS_F(OFF_WCU)[idx] = au;  WS_F(OFF_WCV)[idx] = av;
    }
    if (tid < 32) {
      float bu = 0.f, bv = 0.f;
      #pragma unroll
      for (int f = 0; f < 32; f++) {
        bu = fmaf(ncb2[f], Wu[f*32+tid], bu);
        bv = fmaf(ncb2[f], Wv[f*32+tid], bv);
      }
      WS_F(OFF_BU)[tid] = bu;
      WS_F(OFF_BV)[tid] = bv + m0b1[tid];        // fold mp0_b1 into dst-side
      WS_F(OFF_CPATH)[tid] = ncw1[64+tid]  + ncb1[tid];
      WS_F(OFF_CFREE)[tid] = ncw1[96+tid]  + ncb1[tid];
      WS_F(OFF_CCOL)[tid]  = ncw1[128+tid] + ncb1[tid];
    }
  }
}

// b==0: exclusive scan of cell counts | b==1: CSR build of fixed edges
__global__ __launch_bounds__(256) void k_scan2(char* __restrict__ ws) {
  int b = blockIdx.x, tid = threadIdx.x;
  if (b == 0) {
    __shared__ int part[256];
    int* cnt = WS_I(OFF_CSTART);
    int base = tid * (NCELL/256);
    int sum = 0;
    for (int k = 0; k < NCELL/256; k++) sum += cnt[base+k];
    part[tid] = sum;
    __syncthreads();
    for (int off = 1; off < 256; off <<= 1) {
      int t = (tid >= off) ? part[tid - off] : 0;
      __syncthreads();
      part[tid] += t;
      __syncthreads();
    }
    int run = part[tid] - sum;
    for (int k = 0; k < NCELL/256; k++) {
      int c = cnt[base+k];
      cnt[base+k] = run;
      WS_I(OFF_COFS)[base+k] = run;
      run += c;
    }
    if (tid == 255) cnt[NCELL] = run;
  } else {
    __shared__ int sc[512];
    sc[tid]     = WS_I(OFF_DEG0)[tid];
    sc[256+tid] = WS_I(OFF_DEG0)[256+tid];
    __syncthreads();
    if (tid == 0) {
      int run = 0;
      for (int i = 0; i < 512; i++) { int c = sc[i]; sc[i] = run; run += c; }
      WS_I(OFF_E0START)[512] = run;
    }
    __syncthreads();
    WS_I(OFF_E0START)[tid]     = sc[tid];
    WS_I(OFF_E0START)[256+tid] = sc[256+tid];
    WS_I(OFF_E0OFS)[tid]       = sc[tid];
    WS_I(OFF_E0OFS)[256+tid]   = sc[256+tid];
    __syncthreads();
    int n = *WS_I(OFF_E0C); if (n > E0CAP) n = E0CAP;
    for (int e = tid; e < n; e += 256) {
      int dst = WS_I(OFF_E0D)[e];
      int pos = atomicAdd(&WS_I(OFF_E0OFS)[dst], 1);
      WS_I(OFF_E0CSRS)[pos] = WS_I(OFF_E0S)[e];
    }
  }
}

__global__ __launch_bounds__(256) void k_scatter(char* __restrict__ ws) {
  int j = blockIdx.x * 256 + threadIdx.x;
  if (j >= NCND) return;
  float2 c = ((const float2*)(ws + OFF_CPOS))[j];
  int cx = min(GRID-1, max(0, (int)((c.x - XMINF) * IVCW)));
  int cy = min(GRID-1, max(0, (int)((c.y - YMINF) * IVCW)));
  int pos = atomicAdd(&WS_I(OFF_COFS)[cy*GRID + cx], 1);
  ((float4*)(ws + OFF_SCND))[pos] =
      make_float4(c.x, c.y, c.x*c.x + c.y*c.y, __int_as_float(j));
}

// ---------------- per-loop kernel (round-2 body + early weight prefetch) ----
// 1 dispatch per iteration (persistent-grid fusion measured 2.3x..1.2x WORSE
// across 3 barrier variants — 94MB FETCH / 59MB WRITE regardless of barrier
// ordering semantics; abandoned). Each dispatch starts L2-cold, so the ~28us
// is a serial cold-miss chain; the last 4 rounds of it were the epilogue
// weight matrices. Fix: touch all six 4KB matrices at kernel start (kept
// live via asm volatile) so their HBM misses overlap the kNN scan.
__global__ __launch_bounds__(256, 2) void k_loop_v3(char* __restrict__ ws,
    const float* __restrict__ ncw1, const float* __restrict__ gamma,
    const float* __restrict__ beta, const float* __restrict__ ncw2,
    const float* __restrict__ ncb2, const float* __restrict__ m0w2,
    const float* __restrict__ m0b2, const float* __restrict__ m1w1,
    const float* __restrict__ m1b1, const float* __restrict__ m1w2,
    const float* __restrict__ m1b2, const float* __restrict__ snw,
    const float* __restrict__ snb, float* __restrict__ outp, int l) {
  __shared__ float sD[40];
  __shared__ int   sI[40];
  __shared__ float sMD[10];
  __shared__ int   sMI[10];
  __shared__ int   sbox[9];           // xL,xR,yL,yR, xL2,xR2,yL2,yR2, skip
  __shared__ int   sRC[4];            // per-wave phase-A counts
  __shared__ float sS[4][32];         // per-wave partial S
  int tid = threadIdx.x, lane = tid & 63, wv = tid >> 6;
  int node = blockIdx.x;
  const float4* scnd = (const float4*)(ws + OFF_SCND);
  const int* cst = WS_I(OFF_CSTART);

  int fA = lane & 31;
  const float w0 = ncw1[fA], w1 = ncw1[32+fA];
  const float cp   = WS_F(OFF_CPATH)[fA];
  const float clsF = WS_F(OFF_CFREE)[fA];
  const float clsC = WS_F(OFF_CCOL)[fA];
  const float gm = gamma[fA], bt = beta[fA];
  const float buf = WS_F(OFF_BU)[fA];
  const float bvf = WS_F(OFF_BV)[fA];
  const float* wcu = WS_F(OFF_WCU);
  const float* wcv = WS_F(OFF_WCV);
  const int s0 = WS_I(OFF_E0START)[node], s1 = WS_I(OFF_E0START)[node+1];
  const int nfix = s1 - s0;
  // parallel preload of fixed-edge srcs (lane t holds edge t); tail>64 rare
  const int fsrc = (lane < nfix) ? WS_I(OFF_E0CSRS)[s0 + lane] : -1;

  float* pcur = WS_F((l & 1) ? OFF_PATH2 : OFF_PATH);
  float* pnxt = WS_F((l & 1) ? OFF_PATH  : OFF_PATH2);
  float p0 = pcur[2*node], p1 = pcur[2*node+1];
  float psq = p0*p0 + p1*p1;

  // ---- early weight prefetch: one 16B slice per thread of each 4KB matrix
  // used by S/epilogue. Touched ~10us before use; misses overlap the scan.
  {
    int i4 = tid * 4;                               // 256 threads x 4 floats
    float t = wcu[i4] + wcv[i4] + m0w2[i4] + m1w1[i4] + m1w2[i4] + ncw2[i4];
    if (tid < 64) t += snw[tid*16];                 // 1KB snw
    asm volatile("" :: "v"(t));                     // keep loads live (no DCE)
  }

  // ---- phase A: probe R = 1<<wv in parallel (one radius per wave) ----
  int cx = min(GRID-1, max(0, (int)((p0 - XMINF) * IVCW)));
  int cy = min(GRID-1, max(0, (int)((p1 - YMINF) * IVCW)));
  {
    int Rw = 1 << wv;
    int xA = max(cx-Rw, 0), xB = min(cx+Rw, GRID-1);
    int yA = max(cy-Rw, 0), yB = min(cy+Rw, GRID-1);
    int cnt = 0;
    for (int y = yA + lane; y <= yB; y += 64)
      cnt += cst[y*GRID + xB + 1] - cst[y*GRID + xA];
    #pragma unroll
    for (int off = 32; off >= 1; off >>= 1) cnt += __shfl_xor(cnt, off);
    if (lane == 0) sRC[wv] = cnt;
  }
  __syncthreads();
  if (wv == 0) {
    int R = 0;
    if (sRC[3] >= KK) R = 8;
    if (sRC[2] >= KK) R = 4;
    if (sRC[1] >= KK) R = 2;
    if (sRC[0] >= KK) R = 1;
    int xLa, xRa, yLa, yRa;
    if (R == 0) {                       // rare sparse-region fallback
      R = 16;
      for (;;) {
        xLa = max(cx-R, 0); xRa = min(cx+R, GRID-1);
        yLa = max(cy-R, 0); yRa = min(cy+R, GRID-1);
        int cnt = 0;
        for (int y = yLa + lane; y <= yRa; y += 64)
          cnt += cst[y*GRID + xRa + 1] - cst[y*GRID + xLa];
        #pragma unroll
        for (int off = 32; off >= 1; off >>= 1) cnt += __shfl_xor(cnt, off);
        if (cnt >= KK || R >= GRID) break;
        R <<= 1;
      }
    } else {
      xLa = max(cx-R, 0); xRa = min(cx+R, GRID-1);
      yLa = max(cy-R, 0); yRa = min(cy+R, GRID-1);
    }
    if (lane == 0) { sbox[0]=xLa; sbox[1]=xRa; sbox[2]=yLa; sbox[3]=yRa; }
  }
  __syncthreads();
  int xL = sbox[0], xR = sbox[1], yL = sbox[2], yR = sbox[3];

  // ---- phase B: 4-wave split scan of seed box ----
  float bd[10]; int bi[10];
  #pragma unroll
  for (int k = 0; k < 10; k++) { bd[k] = 3.4e38f; bi[k] = 0x7FFFFFFF; }
  SCAN_BOX4(xL, xR, yL, yR);
  WSTORE10(wv*10);
  __syncthreads();
  if (wv == 0) MERGE40();
  __syncthreads();

  // ---- phase C box + containment test (skip if seed scan already exact) --
  if (tid == 0) {
    float r = sqrtf(sMD[9]) * 1.000002f;
    int xL2 = min(GRID-1, max(0, (int)((p0 - r - XMINF) * IVCW)));
    int xR2 = min(GRID-1, max(0, (int)((p0 + r - XMINF) * IVCW)));
    int yL2 = min(GRID-1, max(0, (int)((p1 - r - YMINF) * IVCW)));
    int yR2 = min(GRID-1, max(0, (int)((p1 + r - YMINF) * IVCW)));
    sbox[4]=xL2; sbox[5]=xR2; sbox[6]=yL2; sbox[7]=yR2;
    sbox[8] = (xL2 >= xL && xR2 <= xR && yL2 >= yL && yR2 <= yR) ? 1 : 0;
  }
  __syncthreads();
  if (!sbox[8]) {
    int xL2 = sbox[4], xR2 = sbox[5], yL2 = sbox[6], yR2 = sbox[7];
    #pragma unroll
    for (int k = 0; k < 10; k++) { bd[k] = 3.4e38f; bi[k] = 0x7FFFFFFF; }
    SCAN_BOX4(xL2, xR2, yL2, yR2);
    WSTORE10(wv*10);
    __syncthreads();
    if (wv == 0) MERGE40();
    __syncthreads();
  }

  // ======== all 4 waves work from here ========

  // dedup kNN vs fixed edges — pure register shfl, no serial loads
  int selIdx = (lane < KK) ? sMI[lane] : 0;
  int srcg   = (lane < KK) ? selIdx + PN : -1;
  int keep   = (lane < KK) ? 1 : 0;
  for (int t = 0; t < min(nfix, 64); t++) {
    int fs = __shfl(fsrc, t);
    if (fs == srcg) keep = 0;
  }
  for (int t = 64; t < nfix; t++) {            // ~never
    int fs = WS_I(OFF_E0CSRS)[s0 + t];
    if (fs == srcg) keep = 0;
  }
  unsigned long long kmask = __ballot(keep);
  int deg = (int)__popcll(kmask) + nfix;

  // parallel prefetch of per-edge data: lane e holds edge e
  //   e in [0,KK): kNN slot e  |  e in [KK,KK+min(nfix,54)): fixed edge e-KK
  int t2 = lane - KK;
  int srcb = __shfl(fsrc, (t2 & 63));          // uniform-exec shfl
  float eq0 = 0.f, eq1 = 0.f; int ecl = 1, eva = 0;
  if (lane < KK) {
    eva = keep;
    if (keep) {
      eq0 = WS_F(OFF_CPOS)[2*selIdx];
      eq1 = WS_F(OFF_CPOS)[2*selIdx+1];
      ecl = (selIdx < NFREE) ? 1 : 2;
    }
  } else if (t2 < nfix) {                      // t2 <= 53 always
    eva = 1;
    if (srcb < PN) { eq0 = pcur[2*srcb]; eq1 = pcur[2*srcb+1]; ecl = 0; }
    else {
      int jj = srcb - PN;
      eq0 = WS_F(OFF_CPOS)[2*jj]; eq1 = WS_F(OFF_CPOS)[2*jj+1];
      ecl = (jj < NFREE) ? 1 : 2;
    }
  }

  // BN path moments (each wave redundantly; pcur is 4KB, L1-hot)
  float pm0=0,pm1=0,pm00=0,pm11=0,pm01=0;
  const float2* pc2 = (const float2*)pcur;
  for (int r2 = lane; r2 < PN; r2 += 64) {
    float2 q = pc2[r2];
    pm0+=q.x; pm1+=q.y; pm00+=q.x*q.x; pm11+=q.y*q.y; pm01+=q.x*q.y;
  }
  #pragma unroll
  for (int off = 32; off >= 1; off >>= 1) {
    pm0+=__shfl_xor(pm0,off); pm1+=__shfl_xor(pm1,off); pm00+=__shfl_xor(pm00,off);
    pm11+=__shfl_xor(pm11,off); pm01+=__shfl_xor(pm01,off);
  }
  float mean, rstd;
  bn_from_moments(ws, w0, w1, cp, clsF, clsC, pm0, pm1, pm00, pm11, pm01,
                  &mean, &rstd);

  // xn_dst and v[dst] (per wave)
  float hD = fmaf(p1, w1, fmaf(p0, w0, cp));
  float xnd = fmaf((hD - mean) * rstd, gm, bt);
  xnd = xnd > 0.f ? xnd : 0.f;
  float av = bvf;
  #pragma unroll
  for (int m = 0; m < 32; m++) av = fmaf(__shfl(xnd, m), wcv[m*32+fA], av);

  // S over edges: 8-way parallel (4 waves x 2 half-waves), uniform trips
  int hf = lane >> 5;
  int Etot = KK + min(nfix, 54);
  int nT = (Etot + 7) >> 3;
  float S = 0.f;
  for (int t = 0; t < nT; t++) {
    int e  = (t << 3) + (wv << 1) + hf;
    int ee = e & 63;
    int   ev = __shfl(eva, ee);
    float q0 = __shfl(eq0, ee), q1 = __shfl(eq1, ee);
    int   ec = __shfl(ecl, ee);
    float clsv = (ec == 0) ? cp : ((ec == 1) ? clsF : clsC);
    float hq = fmaf(q1, w1, fmaf(q0, w0, clsv));
    float xnf = fmaf((hq - mean) * rstd, gm, bt);
    xnf = xnf > 0.f ? xnf : 0.f;
    float au = buf;
    #pragma unroll
    for (int m = 0; m < 32; m++)
      au = fmaf(__shfl(xnf, m, 32), wcu[m*32+fA], au);
    float rr = au + av;
    if (e < Etot && ev && rr > 0.f) S += rr;
  }
  S += __shfl_xor(S, 32);                      // combine half-waves
  if (lane < 32) sS[wv][lane] = S;
  __syncthreads();

  if (wv != 0) return;

  float St = sS[0][fA] + sS[1][fA] + sS[2][fA] + sS[3][fA];
  for (int t = 54; t < nfix; t++) {            // ~never: overflow tail
    int src = WS_I(OFF_E0CSRS)[s0 + t];
    float q0, q1, clsv;
    if (src < PN) { q0 = pcur[2*src]; q1 = pcur[2*src+1]; clsv = cp; }
    else {
      int jj = src - PN;
      q0 = WS_F(OFF_CPOS)[2*jj]; q1 = WS_F(OFF_CPOS)[2*jj+1];
      clsv = (jj < NFREE) ? clsF : clsC;
    }
    float hq = fmaf(q1, w1, fmaf(q0, w0, clsv));
    float xnf = fmaf((hq - mean) * rstd, gm, bt);
    xnf = xnf > 0.f ? xnf : 0.f;
    float au = buf;
    #pragma unroll
    for (int m = 0; m < 32; m++) au = fmaf(__shfl(xnf, m), wcu[m*32+fA], au);
    float rr = au + av;
    if (rr > 0.f) St += rr;
  }

  // epilogue: four 32x32 GEMVs via shfl-dots
  float o = (float)deg * m0b2[fA];
  #pragma unroll
  for (int k = 0; k < 32; k++) o = fmaf(__shfl(St, k), m0w2[k*32+fA], o);
  float t1 = m1b1[fA];
  #pragma unroll
  for (int k = 0; k < 32; k++) t1 = fmaf(__shfl(o, k), m1w1[k*32+fA], t1);
  t1 = t1 > 0.f ? t1 : 0.f;
  float g2 = m1b2[fA];
  #pragma unroll
  for (int k = 0; k < 32; k++) g2 = fmaf(__shfl(t1, k), m1w2[k*32+fA], g2);
  float x = ncb2[fA];
  #pragma unroll
  for (int k = 0; k < 32; k++) x = fmaf(__shfl(xnd, k), ncw2[k*32+fA], x);
  float hh = x + g2;
  float r0 = hh * snw[2*fA], r1 = hh * snw[2*fA+1];
  #pragma unroll
  for (int off = 16; off >= 1; off >>= 1) {
    r0 += __shfl_xor(r0, off);
    r1 += __shfl_xor(r1, off);
  }
  if (lane == 0) {
    float np0, np1;
    if (node == 0 || node == PN-1) { np0 = p0; np1 = p1; }  // endpoints fixed
    else { np0 = snb[0] + r0; np1 = snb[1] + r1; }
    if (l == NLOOP-1) { outp[2*node] = np0; outp[2*node+1] = np1; }
    else              { pnxt[2*node] = np0; pnxt[2*node+1] = np1; }
  }
}

// ---------------- host launch ----------------

extern "C" void kernel_launch(void* const* d_in, const int* in_sizes, int n_in,
                              void* d_out, int out_size, void* d_ws, size_t ws_size,
                              hipStream_t stream) {
  const float* path  = (const float*)d_in[0];
  const float* freep = (const float*)d_in[1];
  const float* collp = (const float*)d_in[2];
  const int*   ei    = (const int*)d_in[4];
  const float* ncw1  = (const float*)d_in[6];
  const float* ncb1  = (const float*)d_in[7];
  const float* gamma = (const float*)d_in[8];
  const float* beta  = (const float*)d_in[9];
  const float* ncw2  = (const float*)d_in[10];
  const float* ncb2  = (const float*)d_in[11];
  const float* m0w1  = (const float*)d_in[12];
  const float* m0b1  = (const float*)d_in[13];
  const float* m0w2  = (const float*)d_in[14];
  const float* m0b2  = (const float*)d_in[15];
  const float* m1w1  = (const float*)d_in[16];
  const float* m1b1  = (const float*)d_in[17];
  const float* m1w2  = (const float*)d_in[18];
  const float* m1b2  = (const float*)d_in[19];
  const float* snw   = (const float*)d_in[20];
  const float* snb   = (const float*)d_in[21];
  char* ws = (char*)d_ws;

  k_init0  <<<65, 256, 0, stream>>>(ws, path);
  k_setupA <<<NCB + NEB + 1, 256, 0, stream>>>(ws, freep, collp, ei,
                                               ncw1, ncb1, m0w1, m0b1, ncw2, ncb2);
  k_scan2  <<<2, 256, 0, stream>>>(ws);
  k_scatter<<<NCB, 256, 0, stream>>>(ws);

  for (int l = 0; l < NLOOP; l++) {
    k_loop_v3<<<PN, 256, 0, stream>>>(ws, ncw1, gamma, beta, ncw2, ncb2,
                                      m0w2, m0b2, m1w1, m1b1, m1w2, m1b2,
                                      snw, snb, (float*)d_out, l);
  }
}

// Round 6
// 258.700 us; speedup vs baseline: 1.9173x; 1.0259x over previous
//
#include <hip/hip_runtime.h>
#include <stdint.h>

// Problem constants (fixed by setup_inputs)
#define PN     512
#define NFREE  50000
#define NCND   100000
#define NNODE  100512
#define NEDGE  300000
#define KK     10
#define NLOOP  5
#define EPSV   1e-5f

#define GRID   128
#define NCELL  (GRID*GRID)

// fixed spatial-hash bounds: candidates ~N(0,1); clamping keeps exactness
#define XMINF  (-6.f)
#define YMINF  (-6.f)
#define SPANF  12.f
#define IVCW   ((float)GRID / SPANF)
#define CW     (SPANF / (float)GRID)

#define HSIZE  8192
#define HMASK  (HSIZE-1)
#define E0CAP  4096
#define EMPTYK 0xFFFFFFFFFFFFFFFFull

#define NCB    ((NCND+255)/256)    // 391
#define NEB    ((NEDGE+255)/256)   // 1172

// workspace layout (bytes) — ~2.7 MB
#define OFF_HASH    ((size_t)0)
#define OFF_CPOS    (OFF_HASH    + (size_t)HSIZE*8)
#define OFF_SCND    (OFF_CPOS    + 800000)               // float4/cand, cell-sorted
#define OFF_CSTART  (OFF_SCND    + 1600000)              // NCELL+1 ints
#define OFF_COFS    (OFF_CSTART  + 65600)
#define OFF_MOM     (OFF_COFS    + 65600)                // 10 floats (cand moments)
#define OFF_WCU     (OFF_MOM     + 64)
#define OFF_WCV     (OFF_WCU     + 4096)
#define OFF_BU      (OFF_WCV     + 4096)
#define OFF_BV      (OFF_BU      + 128)
#define OFF_CPATH   (OFF_BV      + 128)
#define OFF_CFREE   (OFF_CPATH   + 128)
#define OFF_CCOL    (OFF_CFREE   + 128)
#define OFF_PATH    (OFF_CCOL    + 128)                  // 16-aligned
#define OFF_E0S     (OFF_PATH    + 4096)
#define OFF_E0D     (OFF_E0S     + (size_t)E0CAP*4)
#define OFF_DEG0    (OFF_E0D     + (size_t)E0CAP*4)
#define OFF_E0C     (OFF_DEG0    + 2048)
#define OFF_E0START (OFF_E0C     + 64)                   // 513 ints (pad 2112)
#define OFF_E0OFS   (OFF_E0START + 2112)
#define OFF_E0CSRS  (OFF_E0OFS   + 2048)                 // E0CAP ints

// E0S is dead after k_scan2 — reuse as the ping-pong path buffer.
#define OFF_PATH2   OFF_E0S

#define WS_F(o)  ((float*)(ws + (o)))
#define WS_I(o)  ((int*)(ws + (o)))
#define WS_H(o)  ((unsigned long long*)(ws + (o)))

__device__ __forceinline__ bool lexless(float da, int ia, float db, int ib) {
  return (da < db) || (da == db && ia < ib);
}

__device__ __forceinline__ uint32_t hslot(unsigned long long key) {
  return (uint32_t)((key * 0x9E3779B97F4A7C15ull) >> 40) & HMASK;
}

// BN mean/rstd from analytic moments (cand moments in MOM + path moments pm*)
__device__ __forceinline__ void bn_from_moments(const char* ws,
    float w0, float w1, float cp, float clsF, float clsC,
    float pm0, float pm1, float pm00, float pm11, float pm01,
    float* meano, float* rstdo) {
  const float* M = (const float*)(ws + OFF_MOM);
  float sF0=M[0], sF1=M[1], sF00=M[2], sF11=M[3], sF01=M[4];
  float sC0=M[5], sC1=M[6], sC00=M[7], sC11=M[8], sC01=M[9];
  const float NC = (float)(NCND - NFREE);
  float sh  = w0*(sF0+sC0+pm0) + w1*(sF1+sC1+pm1)
            + (float)NFREE*clsF + NC*clsC + (float)PN*cp;
  float sh2 = w0*w0*(sF00+sC00+pm00) + w1*w1*(sF11+sC11+pm11)
            + 2.f*w0*w1*(sF01+sC01+pm01)
            + 2.f*w0*(clsF*sF0 + clsC*sC0 + cp*pm0)
            + 2.f*w1*(clsF*sF1 + clsC*sC1 + cp*pm1)
            + (float)NFREE*clsF*clsF + NC*clsC*clsC + (float)PN*cp*cp;
  float mean = sh  * (1.f / NNODE);
  float ex2  = sh2 * (1.f / NNODE);
  float var  = ex2 - mean * mean;
  *meano = mean;
  *rstdo = 1.0f / sqrtf(var + EPSV);
}

#define INSERT10(d2v, jv)                                                  \
  if (lexless((d2v), (jv), bd[9], bi[9])) {                                \
    bool placed = false;                                                   \
    _Pragma("unroll")                                                      \
    for (int k = 9; k > 0; k--) {                                          \
      bool shift = !placed && lexless((d2v), (jv), bd[k-1], bi[k-1]);      \
      bool here  = !placed && !shift;                                      \
      if (here)       { bd[k] = (d2v); bi[k] = (jv); placed = true; }      \
      else if (shift) { bd[k] = bd[k-1]; bi[k] = bi[k-1]; }                \
    }                                                                      \
    if (!placed) { bd[0] = (d2v); bi[0] = (jv); }                          \
  }

// wave top-10 pop-merge -> LDS slots [base..base+9] (lane r writes rank r)
#define WSTORE10(base) do {                                                \
    float cd[10]; int ci[10];                                              \
    _Pragma("unroll")                                                      \
    for (int k = 0; k < 10; k++) { cd[k] = bd[k]; ci[k] = bi[k]; }         \
    _Pragma("unroll")                                                      \
    for (int r = 0; r < 10; r++) {                                         \
      float md = cd[0]; int mi = ci[0];                                    \
      _Pragma("unroll")                                                    \
      for (int off = 32; off >= 1; off >>= 1) {                            \
        float od = __shfl_xor(md, off);                                    \
        int   oi = __shfl_xor(mi, off);                                    \
        if (lexless(od, oi, md, mi)) { md = od; mi = oi; }                 \
      }                                                                    \
      bool win = (cd[0] == md) && (ci[0] == mi);                           \
      if (win) {                                                           \
        _Pragma("unroll")                                                  \
        for (int k = 0; k < 9; k++) { cd[k] = cd[k+1]; ci[k] = ci[k+1]; }  \
        cd[9] = 3.4e38f; ci[9] = 0x7FFFFFFF;                               \
      }                                                                    \
      if (lane == r) { sD[(base)+r] = md; sI[(base)+r] = mi; }             \
    }                                                                      \
  } while (0)

// exact rank-merge of the 40 LDS entries -> sMD/sMI[0..9].
// Executed by ALL waves redundantly: identical inputs -> identical ranks ->
// all 4 waves write the SAME value to the same slot (benign); each wave then
// reads values its own lanes wrote (wave-ordered LDS, compiler waitcnt).
// This removes the post-merge __syncthreads of the wave0-only scheme.
#define MERGE40ALL() do {                                                  \
    float de = (lane < 40) ? sD[lane] : 3.4e38f;                           \
    int   ie = (lane < 40) ? sI[lane] : 0x7FFFFFFF;                        \
    int rank = 0;                                                          \
    for (int f = 0; f < 40; f++) {                                         \
      float df = sD[f]; int iff = sI[f];                                   \
      bool less = lexless(df, iff, de, ie) ||                              \
                  (df == de && iff == ie && f < lane);                     \
      rank += less ? 1 : 0;                                                \
    }                                                                      \
    if (lane < 40 && rank < 10) { sMD[rank] = de; sMI[rank] = ie; }        \
  } while (0)

// scan rows of box [xA..xB]x[yA..yB] with y % 4 == wv (4-wave split);
// each row is a contiguous scnd span, lanes stride it (coalesced).
#define SCAN_BOX4(xA, xB, yA, yB) do {                                     \
    for (int _y = (yA) + wv; _y <= (yB); _y += 4) {                        \
      int _s = cst[_y*GRID + (xA)], _e = cst[_y*GRID + (xB) + 1];          \
      for (int _t = _s + lane; _t < _e; _t += 64) {                        \
        float4 _q = scnd[_t];                                              \
        float _d2 = (psq + _q.z) - 2.f * fmaf(p1, _q.y, p0 * _q.x);        \
        int _j = __float_as_int(_q.w);                                     \
        INSERT10(_d2, _j);                                                 \
      }                                                                    \
    }                                                                      \
  } while (0)

#define BOX_FROM_R(Rv) do {                                                \
    xL = max(cx-(Rv), 0); xR = min(cx+(Rv), GRID-1);                       \
    yL = max(cy-(Rv), 0); yR = min(cy+(Rv), GRID-1);                       \
  } while (0)

// ---------------- setup kernels ----------------

__global__ __launch_bounds__(256) void k_init0(char* __restrict__ ws,
                                               const float* __restrict__ path_in) {
  unsigned i = blockIdx.x * 256u + threadIdx.x;       // grid = 65 → 16640 ids
  if (i < HSIZE)   WS_H(OFF_HASH)[i] = EMPTYK;
  if (i < NCELL+1) WS_I(OFF_CSTART)[i] = 0;
  if (i < 1024)    WS_F(OFF_PATH)[i] = path_in[i];
  if (i < 512)     WS_I(OFF_DEG0)[i] = 0;
  if (i < 16)      WS_F(OFF_MOM)[i] = 0.f;
  if (i == 0)      *WS_I(OFF_E0C) = 0;
}

// roles: b<NCB cand(pos/moments/hist) | b<NCB+NEB edge filter+dedup | last wprep
__global__ __launch_bounds__(256) void k_setupA(char* __restrict__ ws,
    const float* __restrict__ freep, const float* __restrict__ collp,
    const int* __restrict__ ei,
    const float* __restrict__ ncw1, const float* __restrict__ ncb1,
    const float* __restrict__ m0w1, const float* __restrict__ m0b1,
    const float* __restrict__ ncw2, const float* __restrict__ ncb2) {
  int b = blockIdx.x, tid = threadIdx.x;
  if (b < NCB) {
    __shared__ float s10[4][10];
    int j = b*256 + tid;
    bool valid = (j < NCND);
    float c0 = 0.f, c1 = 0.f;
    if (valid) {
      if (j < NFREE) { c0 = freep[2*j];          c1 = freep[2*j+1]; }
      else           { c0 = collp[2*(j-NFREE)];  c1 = collp[2*(j-NFREE)+1]; }
      ((float2*)(ws + OFF_CPOS))[j] = make_float2(c0, c1);
    }
    bool isF = valid && (j < NFREE), isC = valid && (j >= NFREE);
    float v[10];
    v[0]=isF?c0:0.f; v[1]=isF?c1:0.f; v[2]=isF?c0*c0:0.f; v[3]=isF?c1*c1:0.f; v[4]=isF?c0*c1:0.f;
    v[5]=isC?c0:0.f; v[6]=isC?c1:0.f; v[7]=isC?c0*c0:0.f; v[8]=isC?c1*c1:0.f; v[9]=isC?c0*c1:0.f;
    #pragma unroll
    for (int q = 0; q < 10; q++)
      #pragma unroll
      for (int off = 32; off >= 1; off >>= 1) v[q] += __shfl_xor(v[q], off);
    int wv = tid >> 6, lane = tid & 63;
    if (lane == 0) {
      #pragma unroll
      for (int q = 0; q < 10; q++) s10[wv][q] = v[q];
    }
    if (valid) {
      int cx = min(GRID-1, max(0, (int)((c0 - XMINF) * IVCW)));
      int cy = min(GRID-1, max(0, (int)((c1 - YMINF) * IVCW)));
      atomicAdd(&WS_I(OFF_CSTART)[cy*GRID + cx], 1);
    }
    __syncthreads();
    if (tid < 10)
      atomicAdd(&WS_F(OFF_MOM)[tid], s10[0][tid]+s10[1][tid]+s10[2][tid]+s10[3][tid]);
  } else if (b < NCB + NEB) {
    int e = (b - NCB)*256 + tid;
    if (e >= NEDGE) return;
    int src = ei[e], dst = ei[NEDGE + e];
    if (dst >= PN) return;                         // only dst<PN edges matter
    unsigned long long key = (unsigned long long)src * NNODE + (unsigned long long)dst;
    unsigned long long* hash = WS_H(OFF_HASH);
    uint32_t slot = hslot(key);
    for (;;) {
      unsigned long long prev = atomicCAS(&hash[slot], EMPTYK, key);
      if (prev == EMPTYK) {
        int pos = atomicAdd(WS_I(OFF_E0C), 1);
        if (pos < E0CAP) {
          WS_I(OFF_E0S)[pos] = src;
          WS_I(OFF_E0D)[pos] = dst;
          atomicAdd(&WS_I(OFF_DEG0)[dst], 1);
        }
        break;
      }
      if (prev == key) break;
      slot = (slot + 1) & HMASK;
    }
  } else {
    __shared__ float Wu[1024], Wv[1024];
    for (int it = 0; it < 4; it++) {
      int idx = it*256 + tid, k = idx >> 5, g = idx & 31;
      float a = m0w1[k*32+g], b2 = m0w1[(k+32)*32+g], c = m0w1[(k+64)*32+g];
      Wu[idx] = a + b2;  Wv[idx] = c - a;
    }
    __syncthreads();
    for (int it = 0; it < 4; it++) {
      int idx = it*256 + tid, k = idx >> 5, g = idx & 31;
      float au = 0.f, av = 0.f;
      #pragma unroll
      for (int f = 0; f < 32; f++) {
        float w2 = ncw2[k*32+f];
        au = fmaf(w2, Wu[f*32+g], au);
        av = fmaf(w2, Wv[f*32+g], av);
      }
      WS_F(OFF_WCU)[idx] = au;  WS_F(OFF_WCV)[idx] = av;
    }
    if (tid < 32) {
      float bu = 0.f, bv = 0.f;
      #pragma unroll
      for (int f = 0; f < 32; f++) {
        bu = fmaf(ncb2[f], Wu[f*32+tid], bu);
        bv = fmaf(ncb2[f], Wv[f*32+tid], bv);
      }
      WS_F(OFF_BU)[tid] = bu;
      WS_F(OFF_BV)[tid] = bv + m0b1[tid];        // fold mp0_b1 into dst-side
      WS_F(OFF_CPATH)[tid] = ncw1[64+tid]  + ncb1[tid];
      WS_F(OFF_CFREE)[tid] = ncw1[96+tid]  + ncb1[tid];
      WS_F(OFF_CCOL)[tid]  = ncw1[128+tid] + ncb1[tid];
    }
  }
}

// b==0: exclusive scan of cell counts | b==1: CSR build of fixed edges
__global__ __launch_bounds__(256) void k_scan2(char* __restrict__ ws) {
  int b = blockIdx.x, tid = threadIdx.x;
  if (b == 0) {
    __shared__ int part[256];
    int* cnt = WS_I(OFF_CSTART);
    int base = tid * (NCELL/256);
    int sum = 0;
    for (int k = 0; k < NCELL/256; k++) sum += cnt[base+k];
    part[tid] = sum;
    __syncthreads();
    for (int off = 1; off < 256; off <<= 1) {
      int t = (tid >= off) ? part[tid - off] : 0;
      __syncthreads();
      part[tid] += t;
      __syncthreads();
    }
    int run = part[tid] - sum;
    for (int k = 0; k < NCELL/256; k++) {
      int c = cnt[base+k];
      cnt[base+k] = run;
      WS_I(OFF_COFS)[base+k] = run;
      run += c;
    }
    if (tid == 255) cnt[NCELL] = run;
  } else {
    __shared__ int sc[512];
    sc[tid]     = WS_I(OFF_DEG0)[tid];
    sc[256+tid] = WS_I(OFF_DEG0)[256+tid];
    __syncthreads();
    if (tid == 0) {
      int run = 0;
      for (int i = 0; i < 512; i++) { int c = sc[i]; sc[i] = run; run += c; }
      WS_I(OFF_E0START)[512] = run;
    }
    __syncthreads();
    WS_I(OFF_E0START)[tid]     = sc[tid];
    WS_I(OFF_E0START)[256+tid] = sc[256+tid];
    WS_I(OFF_E0OFS)[tid]       = sc[tid];
    WS_I(OFF_E0OFS)[256+tid]   = sc[256+tid];
    __syncthreads();
    int n = *WS_I(OFF_E0C); if (n > E0CAP) n = E0CAP;
    for (int e = tid; e < n; e += 256) {
      int dst = WS_I(OFF_E0D)[e];
      int pos = atomicAdd(&WS_I(OFF_E0OFS)[dst], 1);
      WS_I(OFF_E0CSRS)[pos] = WS_I(OFF_E0S)[e];
    }
  }
}

__global__ __launch_bounds__(256) void k_scatter(char* __restrict__ ws) {
  int j = blockIdx.x * 256 + threadIdx.x;
  if (j >= NCND) return;
  float2 c = ((const float2*)(ws + OFF_CPOS))[j];
  int cx = min(GRID-1, max(0, (int)((c.x - XMINF) * IVCW)));
  int cy = min(GRID-1, max(0, (int)((c.y - YMINF) * IVCW)));
  int pos = atomicAdd(&WS_I(OFF_COFS)[cy*GRID + cx], 1);
  ((float4*)(ws + OFF_SCND))[pos] =
      make_float4(c.x, c.y, c.x*c.x + c.y*c.y, __int_as_float(j));
}

// ---------------- per-loop kernel v4: 2-barrier common case ----------------
// vs v2/v3 (26us): the 6-barrier phase chain is collapsed.
//  - phase A (count probe + wave0 R-decision + 2 barriers) REPLACED by an
//    analytic box radius from the known N(0,1) candidate density. Exactness
//    is preserved by the existing containment check + two rare backstops
//    (sentinel-in-top10 -> double R; containment fail -> rescan box2).
//  - merge 40->10 runs redundantly on ALL waves writing identical values to
//    the same LDS slots (deterministic), so no post-merge barrier.
// Common case barriers: 1 (post-WSTORE) + 1 (S-reduce) = 2.
__global__ __launch_bounds__(256, 2) void k_loop_v4(char* __restrict__ ws,
    const float* __restrict__ ncw1, const float* __restrict__ gamma,
    const float* __restrict__ beta, const float* __restrict__ ncw2,
    const float* __restrict__ ncb2, const float* __restrict__ m0w2,
    const float* __restrict__ m0b2, const float* __restrict__ m1w1,
    const float* __restrict__ m1b1, const float* __restrict__ m1w2,
    const float* __restrict__ m1b2, const float* __restrict__ snw,
    const float* __restrict__ snb, float* __restrict__ outp, int l) {
  __shared__ float sD[40];
  __shared__ int   sI[40];
  __shared__ float sMD[10];
  __shared__ int   sMI[10];
  __shared__ float sS[4][32];         // per-wave partial S
  int tid = threadIdx.x, lane = tid & 63, wv = tid >> 6;
  int node = blockIdx.x;
  const float4* scnd = (const float4*)(ws + OFF_SCND);
  const int* cst = WS_I(OFF_CSTART);

  int fA = lane & 31;
  const float w0 = ncw1[fA], w1 = ncw1[32+fA];
  const float cp   = WS_F(OFF_CPATH)[fA];
  const float clsF = WS_F(OFF_CFREE)[fA];
  const float clsC = WS_F(OFF_CCOL)[fA];
  const float gm = gamma[fA], bt = beta[fA];
  const float buf = WS_F(OFF_BU)[fA];
  const float bvf = WS_F(OFF_BV)[fA];
  const float* wcu = WS_F(OFF_WCU);
  const float* wcv = WS_F(OFF_WCV);
  const int s0 = WS_I(OFF_E0START)[node], s1 = WS_I(OFF_E0START)[node+1];
  const int nfix = s1 - s0;
  // parallel preload of fixed-edge srcs (lane t holds edge t); tail>64 rare
  const int fsrc = (lane < nfix) ? WS_I(OFF_E0CSRS)[s0 + lane] : -1;

  float* pcur = WS_F((l & 1) ? OFF_PATH2 : OFF_PATH);
  float* pnxt = WS_F((l & 1) ? OFF_PATH  : OFF_PATH2);
  float2 pp = *(const float2*)&pcur[2*node];
  float p0 = pp.x, p1 = pp.y;
  float psq = p0*p0 + p1*p1;

  // ---- analytic seed radius (replaces phase A probe):
  // candidate density lambda(p) = NCND/(2pi) * exp(-|p|^2/2)  [per unit^2]
  // choose smallest R with expected count in (2R+1)w box >= 40 (4x margin
  // over KK=10; undershoot handled exactly by the doubling backstop below)
  int cx = min(GRID-1, max(0, (int)((p0 - XMINF) * IVCW)));
  int cy = min(GRID-1, max(0, (int)((p1 - YMINF) * IVCW)));
  int R;
  {
    float lam = 15915.494f * __expf(-0.5f * psq);      // NCND/(2pi)
    float need = __fsqrt_rn(40.f / lam) * (1.f / CW);  // lower bound on 2R+1
    R = (int)ceilf(0.5f * (need - 1.f));
    R = min(max(R, 1), 32);
  }
  int xL, xR, yL, yR;
  BOX_FROM_R(R);

  // ---- seed scan (4-wave split) + single barrier + all-wave merge ----
  float bd[10]; int bi[10];
  #pragma unroll
  for (int k = 0; k < 10; k++) { bd[k] = 3.4e38f; bi[k] = 0x7FFFFFFF; }
  SCAN_BOX4(xL, xR, yL, yR);
  WSTORE10(wv*10);
  __syncthreads();
  MERGE40ALL();

  // ---- backstop 1 (rare): fewer than 10 points in seed box -> double R.
  // Loop condition is uniform across waves (identical sMD data); the entry
  // barrier guarantees all waves finished reading sD before overwrite.
  while (sMD[9] >= 3.3e38f && R < GRID) {
    R <<= 1;
    BOX_FROM_R(R);
    __syncthreads();
    #pragma unroll
    for (int k = 0; k < 10; k++) { bd[k] = 3.4e38f; bi[k] = 0x7FFFFFFF; }
    SCAN_BOX4(xL, xR, yL, yR);
    WSTORE10(wv*10);
    __syncthreads();
    MERGE40ALL();
  }

  // ---- backstop 2: containment check (exactness). Computed redundantly
  // per wave from identical sMD; branch is block-uniform.
  {
    float r = sqrtf(sMD[9]) * 1.000002f;
    int xL2 = min(GRID-1, max(0, (int)((p0 - r - XMINF) * IVCW)));
    int xR2 = min(GRID-1, max(0, (int)((p0 + r - XMINF) * IVCW)));
    int yL2 = min(GRID-1, max(0, (int)((p1 - r - YMINF) * IVCW)));
    int yR2 = min(GRID-1, max(0, (int)((p1 + r - YMINF) * IVCW)));
    bool contained = (xL2 >= xL && xR2 <= xR && yL2 >= yL && yR2 <= yR);
    if (!contained) {
      __syncthreads();                 // all waves past their merge reads
      #pragma unroll
      for (int k = 0; k < 10; k++) { bd[k] = 3.4e38f; bi[k] = 0x7FFFFFFF; }
      SCAN_BOX4(xL2, xR2, yL2, yR2);
      WSTORE10(wv*10);
      __syncthreads();
      MERGE40ALL();
    }
  }

  // ======== all 4 waves (reading own-wave-written sMI/sMD) ========

  // dedup kNN vs fixed edges — pure register shfl, no serial loads
  int selIdx = (lane < KK) ? sMI[lane] : 0;
  int srcg   = (lane < KK) ? selIdx + PN : -1;
  int keep   = (lane < KK) ? 1 : 0;
  for (int t = 0; t < min(nfix, 64); t++) {
    int fs = __shfl(fsrc, t);
    if (fs == srcg) keep = 0;
  }
  for (int t = 64; t < nfix; t++) {            // ~never
    int fs = WS_I(OFF_E0CSRS)[s0 + t];
    if (fs == srcg) keep = 0;
  }
  unsigned long long kmask = __ballot(keep);
  int deg = (int)__popcll(kmask) + nfix;

  // parallel prefetch of per-edge data: lane e holds edge e
  //   e in [0,KK): kNN slot e  |  e in [KK,KK+min(nfix,54)): fixed edge e-KK
  int t2 = lane - KK;
  int srcb = __shfl(fsrc, (t2 & 63));          // uniform-exec shfl
  float eq0 = 0.f, eq1 = 0.f; int ecl = 1, eva = 0;
  if (lane < KK) {
    eva = keep;
    if (keep) {
      eq0 = WS_F(OFF_CPOS)[2*selIdx];
      eq1 = WS_F(OFF_CPOS)[2*selIdx+1];
      ecl = (selIdx < NFREE) ? 1 : 2;
    }
  } else if (t2 < nfix) {                      // t2 <= 53 always
    eva = 1;
    if (srcb < PN) { eq0 = pcur[2*srcb]; eq1 = pcur[2*srcb+1]; ecl = 0; }
    else {
      int jj = srcb - PN;
      eq0 = WS_F(OFF_CPOS)[2*jj]; eq1 = WS_F(OFF_CPOS)[2*jj+1];
      ecl = (jj < NFREE) ? 1 : 2;
    }
  }

  // BN path moments (each wave redundantly; pcur is 4KB, L1-hot)
  float pm0=0,pm1=0,pm00=0,pm11=0,pm01=0;
  const float2* pc2 = (const float2*)pcur;
  for (int r2 = lane; r2 < PN; r2 += 64) {
    float2 q = pc2[r2];
    pm0+=q.x; pm1+=q.y; pm00+=q.x*q.x; pm11+=q.y*q.y; pm01+=q.x*q.y;
  }
  #pragma unroll
  for (int off = 32; off >= 1; off >>= 1) {
    pm0+=__shfl_xor(pm0,off); pm1+=__shfl_xor(pm1,off); pm00+=__shfl_xor(pm00,off);
    pm11+=__shfl_xor(pm11,off); pm01+=__shfl_xor(pm01,off);
  }
  float mean, rstd;
  bn_from_moments(ws, w0, w1, cp, clsF, clsC, pm0, pm1, pm00, pm11, pm01,
                  &mean, &rstd);

  // xn_dst and v[dst] (per wave)
  float hD = fmaf(p1, w1, fmaf(p0, w0, cp));
  float xnd = fmaf((hD - mean) * rstd, gm, bt);
  xnd = xnd > 0.f ? xnd : 0.f;
  float av = bvf;
  #pragma unroll
  for (int m = 0; m < 32; m++) av = fmaf(__shfl(xnd, m), wcv[m*32+fA], av);

  // S over edges: 8-way parallel (4 waves x 2 half-waves), uniform trips
  int hf = lane >> 5;
  int Etot = KK + min(nfix, 54);
  int nT = (Etot + 7) >> 3;
  float S = 0.f;
  for (int t = 0; t < nT; t++) {
    int e  = (t << 3) + (wv << 1) + hf;
    int ee = e & 63;
    int   ev = __shfl(eva, ee);
    float q0 = __shfl(eq0, ee), q1 = __shfl(eq1, ee);
    int   ec = __shfl(ecl, ee);
    float clsv = (ec == 0) ? cp : ((ec == 1) ? clsF : clsC);
    float hq = fmaf(q1, w1, fmaf(q0, w0, clsv));
    float xnf = fmaf((hq - mean) * rstd, gm, bt);
    xnf = xnf > 0.f ? xnf : 0.f;
    float au = buf;
    #pragma unroll
    for (int m = 0; m < 32; m++)
      au = fmaf(__shfl(xnf, m, 32), wcu[m*32+fA], au);
    float rr = au + av;
    if (e < Etot && ev && rr > 0.f) S += rr;
  }
  S += __shfl_xor(S, 32);                      // combine half-waves
  if (lane < 32) sS[wv][lane] = S;
  __syncthreads();

  if (wv != 0) return;

  float St = sS[0][fA] + sS[1][fA] + sS[2][fA] + sS[3][fA];
  for (int t = 54; t < nfix; t++) {            // ~never: overflow tail
    int src = WS_I(OFF_E0CSRS)[s0 + t];
    float q0, q1, clsv;
    if (src < PN) { q0 = pcur[2*src]; q1 = pcur[2*src+1]; clsv = cp; }
    else {
      int jj = src - PN;
      q0 = WS_F(OFF_CPOS)[2*jj]; q1 = WS_F(OFF_CPOS)[2*jj+1];
      clsv = (jj < NFREE) ? clsF : clsC;
    }
    float hq = fmaf(q1, w1, fmaf(q0, w0, clsv));
    float xnf = fmaf((hq - mean) * rstd, gm, bt);
    xnf = xnf > 0.f ? xnf : 0.f;
    float au = buf;
    #pragma unroll
    for (int m = 0; m < 32; m++) au = fmaf(__shfl(xnf, m), wcu[m*32+fA], au);
    float rr = au + av;
    if (rr > 0.f) St += rr;
  }

  // epilogue: four 32x32 GEMVs via shfl-dots
  float o = (float)deg * m0b2[fA];
  #pragma unroll
  for (int k = 0; k < 32; k++) o = fmaf(__shfl(St, k), m0w2[k*32+fA], o);
  float t1 = m1b1[fA];
  #pragma unroll
  for (int k = 0; k < 32; k++) t1 = fmaf(__shfl(o, k), m1w1[k*32+fA], t1);
  t1 = t1 > 0.f ? t1 : 0.f;
  float g2 = m1b2[fA];
  #pragma unroll
  for (int k = 0; k < 32; k++) g2 = fmaf(__shfl(t1, k), m1w2[k*32+fA], g2);
  float x = ncb2[fA];
  #pragma unroll
  for (int k = 0; k < 32; k++) x = fmaf(__shfl(xnd, k), ncw2[k*32+fA], x);
  float hh = x + g2;
  float r0 = hh * snw[2*fA], r1 = hh * snw[2*fA+1];
  #pragma unroll
  for (int off = 16; off >= 1; off >>= 1) {
    r0 += __shfl_xor(r0, off);
    r1 += __shfl_xor(r1, off);
  }
  if (lane == 0) {
    float np0, np1;
    if (node == 0 || node == PN-1) { np0 = p0; np1 = p1; }  // endpoints fixed
    else { np0 = snb[0] + r0; np1 = snb[1] + r1; }
    if (l == NLOOP-1) { outp[2*node] = np0; outp[2*node+1] = np1; }
    else              { pnxt[2*node] = np0; pnxt[2*node+1] = np1; }
  }
}

// ---------------- host launch ----------------

extern "C" void kernel_launch(void* const* d_in, const int* in_sizes, int n_in,
                              void* d_out, int out_size, void* d_ws, size_t ws_size,
                              hipStream_t stream) {
  const float* path  = (const float*)d_in[0];
  const float* freep = (const float*)d_in[1];
  const float* collp = (const float*)d_in[2];
  const int*   ei    = (const int*)d_in[4];
  const float* ncw1  = (const float*)d_in[6];
  const float* ncb1  = (const float*)d_in[7];
  const float* gamma = (const float*)d_in[8];
  const float* beta  = (const float*)d_in[9];
  const float* ncw2  = (const float*)d_in[10];
  const float* ncb2  = (const float*)d_in[11];
  const float* m0w1  = (const float*)d_in[12];
  const float* m0b1  = (const float*)d_in[13];
  const float* m0w2  = (const float*)d_in[14];
  const float* m0b2  = (const float*)d_in[15];
  const float* m1w1  = (const float*)d_in[16];
  const float* m1b1  = (const float*)d_in[17];
  const float* m1w2  = (const float*)d_in[18];
  const float* m1b2  = (const float*)d_in[19];
  const float* snw   = (const float*)d_in[20];
  const float* snb   = (const float*)d_in[21];
  char* ws = (char*)d_ws;

  k_init0  <<<65, 256, 0, stream>>>(ws, path);
  k_setupA <<<NCB + NEB + 1, 256, 0, stream>>>(ws, freep, collp, ei,
                                               ncw1, ncb1, m0w1, m0b1, ncw2, ncb2);
  k_scan2  <<<2, 256, 0, stream>>>(ws);
  k_scatter<<<NCB, 256, 0, stream>>>(ws);

  for (int l = 0; l < NLOOP; l++) {
    k_loop_v4<<<PN, 256, 0, stream>>>(ws, ncw1, gamma, beta, ncw2, ncb2,
                                      m0w2, m0b2, m1w1, m1b1, m1w2, m1b2,
                                      snw, snb, (float*)d_out, l);
  }
}

// Round 7
// 258.503 us; speedup vs baseline: 1.9187x; 1.0008x over previous
//
#include <hip/hip_runtime.h>
#include <stdint.h>

// Problem constants (fixed by setup_inputs)
#define PN     512
#define NFREE  50000
#define NCND   100000
#define NNODE  100512
#define NEDGE  300000
#define KK     10
#define NLOOP  5
#define EPSV   1e-5f

#define GRID   128
#define NCELL  (GRID*GRID)

// fixed spatial-hash bounds: candidates ~N(0,1); clamping keeps exactness
#define XMINF  (-6.f)
#define YMINF  (-6.f)
#define SPANF  12.f
#define IVCW   ((float)GRID / SPANF)
#define CW     (SPANF / (float)GRID)

#define HSIZE  8192
#define HMASK  (HSIZE-1)
#define E0CAP  4096
#define EMPTYK 0xFFFFFFFFFFFFFFFFull

#define NCB    ((NCND+255)/256)    // 391
#define NEB    ((NEDGE+255)/256)   // 1172

// workspace layout (bytes) — ~2.7 MB
#define OFF_HASH    ((size_t)0)
#define OFF_CPOS    (OFF_HASH    + (size_t)HSIZE*8)
#define OFF_SCND    (OFF_CPOS    + 800000)               // float4/cand, cell-sorted
#define OFF_CSTART  (OFF_SCND    + 1600000)              // NCELL+1 ints
#define OFF_COFS    (OFF_CSTART  + 65600)
#define OFF_MOM     (OFF_COFS    + 65600)                // 10 floats (cand moments)
#define OFF_WCU     (OFF_MOM     + 64)
#define OFF_WCV     (OFF_WCU     + 4096)
#define OFF_BU      (OFF_WCV     + 4096)
#define OFF_BV      (OFF_BU      + 128)
#define OFF_CPATH   (OFF_BV      + 128)
#define OFF_CFREE   (OFF_CPATH   + 128)
#define OFF_CCOL    (OFF_CFREE   + 128)
#define OFF_PATH    (OFF_CCOL    + 128)                  // 16-aligned
#define OFF_E0S     (OFF_PATH    + 4096)
#define OFF_E0D     (OFF_E0S     + (size_t)E0CAP*4)
#define OFF_DEG0    (OFF_E0D     + (size_t)E0CAP*4)
#define OFF_E0C     (OFF_DEG0    + 2048)
#define OFF_E0START (OFF_E0C     + 64)                   // 513 ints (pad 2112)
#define OFF_E0OFS   (OFF_E0START + 2112)
#define OFF_E0CSRS  (OFF_E0OFS   + 2048)                 // E0CAP ints

// E0S is dead after k_scan2 — reuse as the ping-pong path buffer.
#define OFF_PATH2   OFF_E0S

#define WS_F(o)  ((float*)(ws + (o)))
#define WS_I(o)  ((int*)(ws + (o)))
#define WS_H(o)  ((unsigned long long*)(ws + (o)))

__device__ __forceinline__ bool lexless(float da, int ia, float db, int ib) {
  return (da < db) || (da == db && ia < ib);
}

__device__ __forceinline__ uint32_t hslot(unsigned long long key) {
  return (uint32_t)((key * 0x9E3779B97F4A7C15ull) >> 40) & HMASK;
}

// BN mean/rstd from analytic moments (cand moments in MOM + path moments pm*)
__device__ __forceinline__ void bn_from_moments(const char* ws,
    float w0, float w1, float cp, float clsF, float clsC,
    float pm0, float pm1, float pm00, float pm11, float pm01,
    float* meano, float* rstdo) {
  const float* M = (const float*)(ws + OFF_MOM);
  float sF0=M[0], sF1=M[1], sF00=M[2], sF11=M[3], sF01=M[4];
  float sC0=M[5], sC1=M[6], sC00=M[7], sC11=M[8], sC01=M[9];
  const float NC = (float)(NCND - NFREE);
  float sh  = w0*(sF0+sC0+pm0) + w1*(sF1+sC1+pm1)
            + (float)NFREE*clsF + NC*clsC + (float)PN*cp;
  float sh2 = w0*w0*(sF00+sC00+pm00) + w1*w1*(sF11+sC11+pm11)
            + 2.f*w0*w1*(sF01+sC01+pm01)
            + 2.f*w0*(clsF*sF0 + clsC*sC0 + cp*pm0)
            + 2.f*w1*(clsF*sF1 + clsC*sC1 + cp*pm1)
            + (float)NFREE*clsF*clsF + NC*clsC*clsC + (float)PN*cp*cp;
  float mean = sh  * (1.f / NNODE);
  float ex2  = sh2 * (1.f / NNODE);
  float var  = ex2 - mean * mean;
  *meano = mean;
  *rstdo = 1.0f / sqrtf(var + EPSV);
}

#define INSERT10(d2v, jv)                                                  \
  if (lexless((d2v), (jv), bd[9], bi[9])) {                                \
    bool placed = false;                                                   \
    _Pragma("unroll")                                                      \
    for (int k = 9; k > 0; k--) {                                          \
      bool shift = !placed && lexless((d2v), (jv), bd[k-1], bi[k-1]);      \
      bool here  = !placed && !shift;                                      \
      if (here)       { bd[k] = (d2v); bi[k] = (jv); placed = true; }      \
      else if (shift) { bd[k] = bd[k-1]; bi[k] = bi[k-1]; }                \
    }                                                                      \
    if (!placed) { bd[0] = (d2v); bi[0] = (jv); }                          \
  }

// wave top-10 pop-merge -> LDS slots [base..base+9] (lane r writes rank r)
#define WSTORE10(base) do {                                                \
    float cd[10]; int ci[10];                                              \
    _Pragma("unroll")                                                      \
    for (int k = 0; k < 10; k++) { cd[k] = bd[k]; ci[k] = bi[k]; }         \
    _Pragma("unroll")                                                      \
    for (int r = 0; r < 10; r++) {                                         \
      float md = cd[0]; int mi = ci[0];                                    \
      _Pragma("unroll")                                                    \
      for (int off = 32; off >= 1; off >>= 1) {                            \
        float od = __shfl_xor(md, off);                                    \
        int   oi = __shfl_xor(mi, off);                                    \
        if (lexless(od, oi, md, mi)) { md = od; mi = oi; }                 \
      }                                                                    \
      bool win = (cd[0] == md) && (ci[0] == mi);                           \
      if (win) {                                                           \
        _Pragma("unroll")                                                  \
        for (int k = 0; k < 9; k++) { cd[k] = cd[k+1]; ci[k] = ci[k+1]; }  \
        cd[9] = 3.4e38f; ci[9] = 0x7FFFFFFF;                               \
      }                                                                    \
      if (lane == r) { sD[(base)+r] = md; sI[(base)+r] = mi; }             \
    }                                                                      \
  } while (0)

// exact rank-merge of the 40 LDS entries -> sMD/sMI[0..9].
// Executed by ALL waves redundantly: identical inputs -> identical ranks ->
// all 4 waves write the SAME value to the same slot (benign); each wave then
// reads values its own lanes wrote (wave-ordered LDS, compiler waitcnt).
#define MERGE40ALL() do {                                                  \
    float de = (lane < 40) ? sD[lane] : 3.4e38f;                           \
    int   ie = (lane < 40) ? sI[lane] : 0x7FFFFFFF;                        \
    int rank = 0;                                                          \
    for (int f = 0; f < 40; f++) {                                         \
      float df = sD[f]; int iff = sI[f];                                   \
      bool less = lexless(df, iff, de, ie) ||                              \
                  (df == de && iff == ie && f < lane);                     \
      rank += less ? 1 : 0;                                                \
    }                                                                      \
    if (lane < 40 && rank < 10) { sMD[rank] = de; sMI[rank] = ie; }        \
  } while (0)

// scan rows of box [xA..xB]x[yA..yB] with y % 4 == wv (4-wave split);
// each row is a contiguous scnd span, lanes stride it (coalesced).
#define SCAN_BOX4(xA, xB, yA, yB) do {                                     \
    for (int _y = (yA) + wv; _y <= (yB); _y += 4) {                        \
      int _s = cst[_y*GRID + (xA)], _e = cst[_y*GRID + (xB) + 1];          \
      for (int _t = _s + lane; _t < _e; _t += 64) {                        \
        float4 _q = scnd[_t];                                              \
        float _d2 = (psq + _q.z) - 2.f * fmaf(p1, _q.y, p0 * _q.x);        \
        int _j = __float_as_int(_q.w);                                     \
        INSERT10(_d2, _j);                                                 \
      }                                                                    \
    }                                                                      \
  } while (0)

#define BOX_FROM_R(Rv) do {                                                \
    xL = max(cx-(Rv), 0); xR = min(cx+(Rv), GRID-1);                       \
    yL = max(cy-(Rv), 0); yR = min(cy+(Rv), GRID-1);                       \
  } while (0)

// ---------------- setup kernels ----------------

__global__ __launch_bounds__(256) void k_init0(char* __restrict__ ws,
                                               const float* __restrict__ path_in) {
  unsigned i = blockIdx.x * 256u + threadIdx.x;       // grid = 65 → 16640 ids
  if (i < HSIZE)   WS_H(OFF_HASH)[i] = EMPTYK;
  if (i < NCELL+1) WS_I(OFF_CSTART)[i] = 0;
  if (i < 1024)    WS_F(OFF_PATH)[i] = path_in[i];
  if (i < 512)     WS_I(OFF_DEG0)[i] = 0;
  if (i < 16)      WS_F(OFF_MOM)[i] = 0.f;
  if (i == 0)      *WS_I(OFF_E0C) = 0;
}

// roles: b<NCB cand(pos/moments/hist) | b<NCB+NEB edge filter+dedup | last wprep
__global__ __launch_bounds__(256) void k_setupA(char* __restrict__ ws,
    const float* __restrict__ freep, const float* __restrict__ collp,
    const int* __restrict__ ei,
    const float* __restrict__ ncw1, const float* __restrict__ ncb1,
    const float* __restrict__ m0w1, const float* __restrict__ m0b1,
    const float* __restrict__ ncw2, const float* __restrict__ ncb2) {
  int b = blockIdx.x, tid = threadIdx.x;
  if (b < NCB) {
    __shared__ float s10[4][10];
    int j = b*256 + tid;
    bool valid = (j < NCND);
    float c0 = 0.f, c1 = 0.f;
    if (valid) {
      if (j < NFREE) { c0 = freep[2*j];          c1 = freep[2*j+1]; }
      else           { c0 = collp[2*(j-NFREE)];  c1 = collp[2*(j-NFREE)+1]; }
      ((float2*)(ws + OFF_CPOS))[j] = make_float2(c0, c1);
    }
    bool isF = valid && (j < NFREE), isC = valid && (j >= NFREE);
    float v[10];
    v[0]=isF?c0:0.f; v[1]=isF?c1:0.f; v[2]=isF?c0*c0:0.f; v[3]=isF?c1*c1:0.f; v[4]=isF?c0*c1:0.f;
    v[5]=isC?c0:0.f; v[6]=isC?c1:0.f; v[7]=isC?c0*c0:0.f; v[8]=isC?c1*c1:0.f; v[9]=isC?c0*c1:0.f;
    #pragma unroll
    for (int q = 0; q < 10; q++)
      #pragma unroll
      for (int off = 32; off >= 1; off >>= 1) v[q] += __shfl_xor(v[q], off);
    int wv = tid >> 6, lane = tid & 63;
    if (lane == 0) {
      #pragma unroll
      for (int q = 0; q < 10; q++) s10[wv][q] = v[q];
    }
    if (valid) {
      int cx = min(GRID-1, max(0, (int)((c0 - XMINF) * IVCW)));
      int cy = min(GRID-1, max(0, (int)((c1 - YMINF) * IVCW)));
      atomicAdd(&WS_I(OFF_CSTART)[cy*GRID + cx], 1);
    }
    __syncthreads();
    if (tid < 10)
      atomicAdd(&WS_F(OFF_MOM)[tid], s10[0][tid]+s10[1][tid]+s10[2][tid]+s10[3][tid]);
  } else if (b < NCB + NEB) {
    int e = (b - NCB)*256 + tid;
    if (e >= NEDGE) return;
    // dst-first early-out: 99.5% of edges fail dst<PN — skip the src stream
    // read for those (halves this kernel's cold-stream traffic).
    int dst = ei[NEDGE + e];
    if (dst >= PN) return;                         // only dst<PN edges matter
    int src = ei[e];
    unsigned long long key = (unsigned long long)src * NNODE + (unsigned long long)dst;
    unsigned long long* hash = WS_H(OFF_HASH);
    uint32_t slot = hslot(key);
    for (;;) {
      unsigned long long prev = atomicCAS(&hash[slot], EMPTYK, key);
      if (prev == EMPTYK) {
        int pos = atomicAdd(WS_I(OFF_E0C), 1);
        if (pos < E0CAP) {
          WS_I(OFF_E0S)[pos] = src;
          WS_I(OFF_E0D)[pos] = dst;
          atomicAdd(&WS_I(OFF_DEG0)[dst], 1);
        }
        break;
      }
      if (prev == key) break;
      slot = (slot + 1) & HMASK;
    }
  } else {
    __shared__ float Wu[1024], Wv[1024];
    for (int it = 0; it < 4; it++) {
      int idx = it*256 + tid, k = idx >> 5, g = idx & 31;
      float a = m0w1[k*32+g], b2 = m0w1[(k+32)*32+g], c = m0w1[(k+64)*32+g];
      Wu[idx] = a + b2;  Wv[idx] = c - a;
    }
    __syncthreads();
    for (int it = 0; it < 4; it++) {
      int idx = it*256 + tid, k = idx >> 5, g = idx & 31;
      float au = 0.f, av = 0.f;
      #pragma unroll
      for (int f = 0; f < 32; f++) {
        float w2 = ncw2[k*32+f];
        au = fmaf(w2, Wu[f*32+g], au);
        av = fmaf(w2, Wv[f*32+g], av);
      }
      WS_F(OFF_WCU)[idx] = au;  WS_F(OFF_WCV)[idx] = av;
    }
    if (tid < 32) {
      float bu = 0.f, bv = 0.f;
      #pragma unroll
      for (int f = 0; f < 32; f++) {
        bu = fmaf(ncb2[f], Wu[f*32+tid], bu);
        bv = fmaf(ncb2[f], Wv[f*32+tid], bv);
      }
      WS_F(OFF_BU)[tid] = bu;
      WS_F(OFF_BV)[tid] = bv + m0b1[tid];        // fold mp0_b1 into dst-side
      WS_F(OFF_CPATH)[tid] = ncw1[64+tid]  + ncb1[tid];
      WS_F(OFF_CFREE)[tid] = ncw1[96+tid]  + ncb1[tid];
      WS_F(OFF_CCOL)[tid]  = ncw1[128+tid] + ncb1[tid];
    }
  }
}

// b==0: exclusive scan of cell counts | b==1: CSR build of fixed edges
__global__ __launch_bounds__(256) void k_scan2(char* __restrict__ ws) {
  int b = blockIdx.x, tid = threadIdx.x;
  if (b == 0) {
    __shared__ int part[256];
    int* cnt = WS_I(OFF_CSTART);
    int base = tid * (NCELL/256);
    int sum = 0;
    for (int k = 0; k < NCELL/256; k++) sum += cnt[base+k];
    part[tid] = sum;
    __syncthreads();
    for (int off = 1; off < 256; off <<= 1) {
      int t = (tid >= off) ? part[tid - off] : 0;
      __syncthreads();
      part[tid] += t;
      __syncthreads();
    }
    int run = part[tid] - sum;
    for (int k = 0; k < NCELL/256; k++) {
      int c = cnt[base+k];
      cnt[base+k] = run;
      WS_I(OFF_COFS)[base+k] = run;
      run += c;
    }
    if (tid == 255) cnt[NCELL] = run;
  } else {
    __shared__ int sc[512];
    sc[tid]     = WS_I(OFF_DEG0)[tid];
    sc[256+tid] = WS_I(OFF_DEG0)[256+tid];
    __syncthreads();
    if (tid == 0) {
      int run = 0;
      for (int i = 0; i < 512; i++) { int c = sc[i]; sc[i] = run; run += c; }
      WS_I(OFF_E0START)[512] = run;
    }
    __syncthreads();
    WS_I(OFF_E0START)[tid]     = sc[tid];
    WS_I(OFF_E0START)[256+tid] = sc[256+tid];
    WS_I(OFF_E0OFS)[tid]       = sc[tid];
    WS_I(OFF_E0OFS)[256+tid]   = sc[256+tid];
    __syncthreads();
    int n = *WS_I(OFF_E0C); if (n > E0CAP) n = E0CAP;
    for (int e = tid; e < n; e += 256) {
      int dst = WS_I(OFF_E0D)[e];
      int pos = atomicAdd(&WS_I(OFF_E0OFS)[dst], 1);
      WS_I(OFF_E0CSRS)[pos] = WS_I(OFF_E0S)[e];
    }
  }
}

// scatter reads freep/collp directly (skips the cpos dependency round)
__global__ __launch_bounds__(256) void k_scatter(char* __restrict__ ws,
    const float* __restrict__ freep, const float* __restrict__ collp) {
  int j = blockIdx.x * 256 + threadIdx.x;
  if (j >= NCND) return;
  float c0, c1;
  if (j < NFREE) { c0 = freep[2*j];         c1 = freep[2*j+1]; }
  else           { c0 = collp[2*(j-NFREE)]; c1 = collp[2*(j-NFREE)+1]; }
  int cx = min(GRID-1, max(0, (int)((c0 - XMINF) * IVCW)));
  int cy = min(GRID-1, max(0, (int)((c1 - YMINF) * IVCW)));
  int pos = atomicAdd(&WS_I(OFF_COFS)[cy*GRID + cx], 1);
  ((float4*)(ws + OFF_SCND))[pos] =
      make_float4(c0, c1, c0*c0 + c1*c1, __int_as_float(j));
}

// ---------------- per-loop kernel v4 body (2-barrier common case) ----------
__global__ __launch_bounds__(256, 2) void k_loop_v4(char* __restrict__ ws,
    const float* __restrict__ ncw1, const float* __restrict__ gamma,
    const float* __restrict__ beta, const float* __restrict__ ncw2,
    const float* __restrict__ ncb2, const float* __restrict__ m0w2,
    const float* __restrict__ m0b2, const float* __restrict__ m1w1,
    const float* __restrict__ m1b1, const float* __restrict__ m1w2,
    const float* __restrict__ m1b2, const float* __restrict__ snw,
    const float* __restrict__ snb, float* __restrict__ outp, int l) {
  __shared__ float sD[40];
  __shared__ int   sI[40];
  __shared__ float sMD[10];
  __shared__ int   sMI[10];
  __shared__ float sS[4][32];         // per-wave partial S
  int tid = threadIdx.x, lane = tid & 63, wv = tid >> 6;
  int node = blockIdx.x;
  const float4* scnd = (const float4*)(ws + OFF_SCND);
  const int* cst = WS_I(OFF_CSTART);

  int fA = lane & 31;
  const float w0 = ncw1[fA], w1 = ncw1[32+fA];
  const float cp   = WS_F(OFF_CPATH)[fA];
  const float clsF = WS_F(OFF_CFREE)[fA];
  const float clsC = WS_F(OFF_CCOL)[fA];
  const float gm = gamma[fA], bt = beta[fA];
  const float buf = WS_F(OFF_BU)[fA];
  const float bvf = WS_F(OFF_BV)[fA];
  const float* wcu = WS_F(OFF_WCU);
  const float* wcv = WS_F(OFF_WCV);
  const int s0 = WS_I(OFF_E0START)[node], s1 = WS_I(OFF_E0START)[node+1];
  const int nfix = s1 - s0;
  // parallel preload of fixed-edge srcs (lane t holds edge t); tail>64 rare
  const int fsrc = (lane < nfix) ? WS_I(OFF_E0CSRS)[s0 + lane] : -1;

  float* pcur = WS_F((l & 1) ? OFF_PATH2 : OFF_PATH);
  float* pnxt = WS_F((l & 1) ? OFF_PATH  : OFF_PATH2);
  float2 pp = *(const float2*)&pcur[2*node];
  float p0 = pp.x, p1 = pp.y;
  float psq = p0*p0 + p1*p1;

  // analytic seed radius (no probe): lambda(p) = NCND/(2pi)*exp(-|p|^2/2);
  // smallest R with expected box count >= 40 (4x margin over KK=10).
  int cx = min(GRID-1, max(0, (int)((p0 - XMINF) * IVCW)));
  int cy = min(GRID-1, max(0, (int)((p1 - YMINF) * IVCW)));
  int R;
  {
    float lam = 15915.494f * __expf(-0.5f * psq);      // NCND/(2pi)
    float need = __fsqrt_rn(40.f / lam) * (1.f / CW);  // lower bound on 2R+1
    R = (int)ceilf(0.5f * (need - 1.f));
    R = min(max(R, 1), 32);
  }
  int xL, xR, yL, yR;
  BOX_FROM_R(R);

  // seed scan (4-wave split) + single barrier + all-wave merge
  float bd[10]; int bi[10];
  #pragma unroll
  for (int k = 0; k < 10; k++) { bd[k] = 3.4e38f; bi[k] = 0x7FFFFFFF; }
  SCAN_BOX4(xL, xR, yL, yR);
  WSTORE10(wv*10);
  __syncthreads();
  MERGE40ALL();

  // backstop 1 (rare): <10 points in seed box -> double R (uniform branch)
  while (sMD[9] >= 3.3e38f && R < GRID) {
    R <<= 1;
    BOX_FROM_R(R);
    __syncthreads();
    #pragma unroll
    for (int k = 0; k < 10; k++) { bd[k] = 3.4e38f; bi[k] = 0x7FFFFFFF; }
    SCAN_BOX4(xL, xR, yL, yR);
    WSTORE10(wv*10);
    __syncthreads();
    MERGE40ALL();
  }

  // backstop 2: containment check (exactness; block-uniform branch)
  {
    float r = sqrtf(sMD[9]) * 1.000002f;
    int xL2 = min(GRID-1, max(0, (int)((p0 - r - XMINF) * IVCW)));
    int xR2 = min(GRID-1, max(0, (int)((p0 + r - XMINF) * IVCW)));
    int yL2 = min(GRID-1, max(0, (int)((p1 - r - YMINF) * IVCW)));
    int yR2 = min(GRID-1, max(0, (int)((p1 + r - YMINF) * IVCW)));
    bool contained = (xL2 >= xL && xR2 <= xR && yL2 >= yL && yR2 <= yR);
    if (!contained) {
      __syncthreads();                 // all waves past their merge reads
      #pragma unroll
      for (int k = 0; k < 10; k++) { bd[k] = 3.4e38f; bi[k] = 0x7FFFFFFF; }
      SCAN_BOX4(xL2, xR2, yL2, yR2);
      WSTORE10(wv*10);
      __syncthreads();
      MERGE40ALL();
    }
  }

  // ======== all 4 waves (reading own-wave-written sMI/sMD) ========

  // dedup kNN vs fixed edges — pure register shfl, no serial loads
  int selIdx = (lane < KK) ? sMI[lane] : 0;
  int srcg   = (lane < KK) ? selIdx + PN : -1;
  int keep   = (lane < KK) ? 1 : 0;
  for (int t = 0; t < min(nfix, 64); t++) {
    int fs = __shfl(fsrc, t);
    if (fs == srcg) keep = 0;
  }
  for (int t = 64; t < nfix; t++) {            // ~never
    int fs = WS_I(OFF_E0CSRS)[s0 + t];
    if (fs == srcg) keep = 0;
  }
  unsigned long long kmask = __ballot(keep);
  int deg = (int)__popcll(kmask) + nfix;

  // parallel prefetch of per-edge data: lane e holds edge e
  int t2 = lane - KK;
  int srcb = __shfl(fsrc, (t2 & 63));          // uniform-exec shfl
  float eq0 = 0.f, eq1 = 0.f; int ecl = 1, eva = 0;
  if (lane < KK) {
    eva = keep;
    if (keep) {
      eq0 = WS_F(OFF_CPOS)[2*selIdx];
      eq1 = WS_F(OFF_CPOS)[2*selIdx+1];
      ecl = (selIdx < NFREE) ? 1 : 2;
    }
  } else if (t2 < nfix) {                      // t2 <= 53 always
    eva = 1;
    if (srcb < PN) { eq0 = pcur[2*srcb]; eq1 = pcur[2*srcb+1]; ecl = 0; }
    else {
      int jj = srcb - PN;
      eq0 = WS_F(OFF_CPOS)[2*jj]; eq1 = WS_F(OFF_CPOS)[2*jj+1];
      ecl = (jj < NFREE) ? 1 : 2;
    }
  }

  // BN path moments (each wave redundantly; pcur is 4KB, L1-hot)
  float pm0=0,pm1=0,pm00=0,pm11=0,pm01=0;
  const float2* pc2 = (const float2*)pcur;
  for (int r2 = lane; r2 < PN; r2 += 64) {
    float2 q = pc2[r2];
    pm0+=q.x; pm1+=q.y; pm00+=q.x*q.x; pm11+=q.y*q.y; pm01+=q.x*q.y;
  }
  #pragma unroll
  for (int off = 32; off >= 1; off >>= 1) {
    pm0+=__shfl_xor(pm0,off); pm1+=__shfl_xor(pm1,off); pm00+=__shfl_xor(pm00,off);
    pm11+=__shfl_xor(pm11,off); pm01+=__shfl_xor(pm01,off);
  }
  float mean, rstd;
  bn_from_moments(ws, w0, w1, cp, clsF, clsC, pm0, pm1, pm00, pm11, pm01,
                  &mean, &rstd);

  // xn_dst and v[dst] (per wave)
  float hD = fmaf(p1, w1, fmaf(p0, w0, cp));
  float xnd = fmaf((hD - mean) * rstd, gm, bt);
  xnd = xnd > 0.f ? xnd : 0.f;
  float av = bvf;
  #pragma unroll
  for (int m = 0; m < 32; m++) av = fmaf(__shfl(xnd, m), wcv[m*32+fA], av);

  // S over edges: 8-way parallel (4 waves x 2 half-waves), uniform trips
  int hf = lane >> 5;
  int Etot = KK + min(nfix, 54);
  int nT = (Etot + 7) >> 3;
  float S = 0.f;
  for (int t = 0; t < nT; t++) {
    int e  = (t << 3) + (wv << 1) + hf;
    int ee = e & 63;
    int   ev = __shfl(eva, ee);
    float q0 = __shfl(eq0, ee), q1 = __shfl(eq1, ee);
    int   ec = __shfl(ecl, ee);
    float clsv = (ec == 0) ? cp : ((ec == 1) ? clsF : clsC);
    float hq = fmaf(q1, w1, fmaf(q0, w0, clsv));
    float xnf = fmaf((hq - mean) * rstd, gm, bt);
    xnf = xnf > 0.f ? xnf : 0.f;
    float au = buf;
    #pragma unroll
    for (int m = 0; m < 32; m++)
      au = fmaf(__shfl(xnf, m, 32), wcu[m*32+fA], au);
    float rr = au + av;
    if (e < Etot && ev && rr > 0.f) S += rr;
  }
  S += __shfl_xor(S, 32);                      // combine half-waves
  if (lane < 32) sS[wv][lane] = S;
  __syncthreads();

  if (wv != 0) return;

  float St = sS[0][fA] + sS[1][fA] + sS[2][fA] + sS[3][fA];
  for (int t = 54; t < nfix; t++) {            // ~never: overflow tail
    int src = WS_I(OFF_E0CSRS)[s0 + t];
    float q0, q1, clsv;
    if (src < PN) { q0 = pcur[2*src]; q1 = pcur[2*src+1]; clsv = cp; }
    else {
      int jj = src - PN;
      q0 = WS_F(OFF_CPOS)[2*jj]; q1 = WS_F(OFF_CPOS)[2*jj+1];
      clsv = (jj < NFREE) ? clsF : clsC;
    }
    float hq = fmaf(q1, w1, fmaf(q0, w0, clsv));
    float xnf = fmaf((hq - mean) * rstd, gm, bt);
    xnf = xnf > 0.f ? xnf : 0.f;
    float au = buf;
    #pragma unroll
    for (int m = 0; m < 32; m++) au = fmaf(__shfl(xnf, m), wcu[m*32+fA], au);
    float rr = au + av;
    if (rr > 0.f) St += rr;
  }

  // epilogue: four 32x32 GEMVs via shfl-dots
  float o = (float)deg * m0b2[fA];
  #pragma unroll
  for (int k = 0; k < 32; k++) o = fmaf(__shfl(St, k), m0w2[k*32+fA], o);
  float t1 = m1b1[fA];
  #pragma unroll
  for (int k = 0; k < 32; k++) t1 = fmaf(__shfl(o, k), m1w1[k*32+fA], t1);
  t1 = t1 > 0.f ? t1 : 0.f;
  float g2 = m1b2[fA];
  #pragma unroll
  for (int k = 0; k < 32; k++) g2 = fmaf(__shfl(t1, k), m1w2[k*32+fA], g2);
  float x = ncb2[fA];
  #pragma unroll
  for (int k = 0; k < 32; k++) x = fmaf(__shfl(xnd, k), ncw2[k*32+fA], x);
  float hh = x + g2;
  float r0 = hh * snw[2*fA], r1 = hh * snw[2*fA+1];
  #pragma unroll
  for (int off = 16; off >= 1; off >>= 1) {
    r0 += __shfl_xor(r0, off);
    r1 += __shfl_xor(r1, off);
  }
  if (lane == 0) {
    float np0, np1;
    if (node == 0 || node == PN-1) { np0 = p0; np1 = p1; }  // endpoints fixed
    else { np0 = snb[0] + r0; np1 = snb[1] + r1; }
    if (l == NLOOP-1) { outp[2*node] = np0; outp[2*node+1] = np1; }
    else              { pnxt[2*node] = np0; pnxt[2*node+1] = np1; }
  }
}

// ---------------- host launch ----------------

extern "C" void kernel_launch(void* const* d_in, const int* in_sizes, int n_in,
                              void* d_out, int out_size, void* d_ws, size_t ws_size,
                              hipStream_t stream) {
  const float* path  = (const float*)d_in[0];
  const float* freep = (const float*)d_in[1];
  const float* collp = (const float*)d_in[2];
  const int*   ei    = (const int*)d_in[4];
  const float* ncw1  = (const float*)d_in[6];
  const float* ncb1  = (const float*)d_in[7];
  const float* gamma = (const float*)d_in[8];
  const float* beta  = (const float*)d_in[9];
  const float* ncw2  = (const float*)d_in[10];
  const float* ncb2  = (const float*)d_in[11];
  const float* m0w1  = (const float*)d_in[12];
  const float* m0b1  = (const float*)d_in[13];
  const float* m0w2  = (const float*)d_in[14];
  const float* m0b2  = (const float*)d_in[15];
  const float* m1w1  = (const float*)d_in[16];
  const float* m1b1  = (const float*)d_in[17];
  const float* m1w2  = (const float*)d_in[18];
  const float* m1b2  = (const float*)d_in[19];
  const float* snw   = (const float*)d_in[20];
  const float* snb   = (const float*)d_in[21];
  char* ws = (char*)d_ws;

  k_init0  <<<65, 256, 0, stream>>>(ws, path);
  k_setupA <<<NCB + NEB + 1, 256, 0, stream>>>(ws, freep, collp, ei,
                                               ncw1, ncb1, m0w1, m0b1, ncw2, ncb2);
  k_scan2  <<<2, 256, 0, stream>>>(ws);
  k_scatter<<<NCB, 256, 0, stream>>>(ws, freep, collp);

  for (int l = 0; l < NLOOP; l++) {
    k_loop_v4<<<PN, 256, 0, stream>>>(ws, ncw1, gamma, beta, ncw2, ncb2,
                                      m0w2, m0b2, m1w1, m1b1, m1w2, m1b2,
                                      snw, snb, (float*)d_out, l);
  }
}